// Round 11
// baseline (141.492 us; speedup 1.0000x reference)
//
#include <hip/hip_runtime.h>
#include <math.h>

// ---------------------------------------------------------------------------
// Aggre_social on MI355X — round 11: core = round-8 body + no-2-instance-tail
// grid (2112 blocks, early exit) + unrolled alpha re-gather; hI2final weight
// amortization (W2+W3 resident, 4 groups/block); build_active merged into
// setup; social builds B-images in-kernel (prepack2 deleted). 7 dispatches.
// ws layout unchanged (21,604,096 B proven cap).
// Sizes: NU=NI=50000, NR=5, D=64, B=512, LS=32, LI=64.
// ---------------------------------------------------------------------------

#define NII 50000
#define BB 512
#define LSS 32
#define NT 16896   // 512 self + 16384 neighbor instances

typedef short short8 __attribute__((ext_vector_type(8)));
typedef float f32x4 __attribute__((ext_vector_type(4)));

static __device__ __forceinline__ bool mread(const void* p, long i, int mode) {
  if (mode == 0) return ((const int*)p)[i] != 0;       // int32 storage
  if (mode == 2) return ((const float*)p)[i] != 0.0f;  // f32 storage
  return ((const unsigned char*)p)[i] != 0;            // byte storage
}

static __device__ __forceinline__ float wsum(float v) {
#pragma unroll
  for (int s = 1; s < 64; s <<= 1) v += __shfl_xor(v, s);
  return v;
}
static __device__ __forceinline__ float wmax(float v) {
#pragma unroll
  for (int s = 1; s < 64; s <<= 1) v = fmaxf(v, __shfl_xor(v, s));
  return v;
}
static __device__ __forceinline__ float rsum16(float v) {
#pragma unroll
  for (int s = 1; s < 16; s <<= 1) v += __shfl_xor(v, s);
  return v;
}

// f32 -> bf16 (round-to-nearest-even), as raw short.
static __device__ __forceinline__ short bf16rne(float f) {
  unsigned u = __float_as_uint(f);
  u = (u + 0x7FFFu + ((u >> 16) & 1u)) >> 16;
  return (short)u;
}
static __device__ __forceinline__ float bf16tof(short h) {
  return __uint_as_float(((unsigned)(unsigned short)h) << 16);
}

// Intra-wave LDS write->read fence.
static __device__ __forceinline__ void wave_fence() {
  asm volatile("s_waitcnt lgkmcnt(0)" ::: "memory");
  __builtin_amdgcn_sched_barrier(0);
}

// ---------------------------------------------------------------------------
// K0: fused setup. block 0: mask-format detect; block 1: RW1g matvec;
// block 2: prepack item-att B-images + W1 hi/lo split; blocks 3..68: build
// active instance list (local mask-format detect per block).   <<<69,256>>>
// ---------------------------------------------------------------------------
__global__ void setup_kernel(const unsigned int* __restrict__ sm,
                             int* __restrict__ flag,
                             const float* __restrict__ rating_w,
                             const float* __restrict__ w1,
                             const float* __restrict__ b1,
                             float* __restrict__ RW1g,
                             const float* __restrict__ A1w,
                             const float* __restrict__ A2w,
                             short* __restrict__ B1,
                             short* __restrict__ B2,
                             short* __restrict__ W1hi,
                             short* __restrict__ W1lo,
                             const int* __restrict__ nodes,
                             const int* __restrict__ social_hist,
                             int* __restrict__ counter,
                             int* __restrict__ list,
                             int* __restrict__ aUid) {
  const int tid = threadIdx.x;
  if (blockIdx.x == 0) {
    __shared__ int notInt, notFloat;
    if (tid == 0) { notInt = 0; notFloat = 0; }
    __syncthreads();
    int ni = 0, nf = 0;
    for (int i = tid; i < 4096; i += 256) {
      unsigned int x = sm[i];
      if (x > 1u) ni = 1;
      if (x != 0u && x != 0x3F800000u) nf = 1;
    }
    if (ni) atomicOr(&notInt, 1);
    if (nf) atomicOr(&notFloat, 1);
    __syncthreads();
    if (tid == 0) flag[0] = notInt ? (notFloat ? 1 : 2) : 0;
  } else if (blockIdx.x == 1) {
    for (int t = tid; t < 320; t += 256) {
      const int r = t >> 6, c = t & 63;
      float acc = b1[c];
      for (int k = 0; k < 64; ++k)
        acc = fmaf(rating_w[r * 64 + k], w1[(64 + k) * 64 + c], acc);
      RW1g[r * 64 + c] = acc;
    }
  } else if (blockIdx.x == 2) {
    for (int idx = tid; idx < 4096; idx += 256) {
      int e = idx & 7, g = idx >> 3;
      int l = g & 63, q = g >> 6;        // q = kb*4+nb
      int kb = q >> 2, nb = q & 3;
      int k = kb * 32 + ((l >> 4) & 3) * 8 + e;
      int col = nb * 16 + (l & 15);
      B1[idx] = bf16rne(A1w[k * 64 + col]);
      B2[idx] = bf16rne(A2w[k * 64 + col]);
      float a = w1[k * 64 + col];
      short h = bf16rne(a);
      W1hi[idx] = h;
      W1lo[idx] = bf16rne(a - bf16tof(h));
    }
  } else {
    // build active list; per-block local mask-format detect (no dependency
    // on block 0 — blocks may run in any order).
    __shared__ int nI, nF;
    if (tid == 0) { nI = 0; nF = 0; }
    __syncthreads();
    int ni = 0, nf = 0;
    for (int i = tid; i < 4096; i += 256) {
      unsigned int x = sm[i];
      if (x > 1u) ni = 1;
      if (x != 0u && x != 0x3F800000u) nf = 1;
    }
    if (ni) atomicOr(&nI, 1);
    if (nf) atomicOr(&nF, 1);
    __syncthreads();
    const int mode = nI ? (nF ? 1 : 2) : 0;
    const int t = (blockIdx.x - 3) * 256 + tid;
    if (t < NT) {
      int uid;
      bool active;
      if (t < BB) {
        active = true;
        uid = nodes[t];
      } else {
        int nb = t - BB;
        int b = nb >> 5, l = nb & 31;
        long mi = (long)nodes[b] * LSS + l;
        active = mread((const void*)sm, mi, mode);
        uid = active ? social_hist[mi] : 0;
      }
      if (active) {
        int pos = atomicAdd(counter, 1);
        list[pos] = t;
        aUid[pos] = uid;
      }
    }
  }
}

// ---------------------------------------------------------------------------
// K2: xbase[50000][64] = item_w @ W1[0:64] via split-bf16 MFMA.
// ---------------------------------------------------------------------------
__global__ __launch_bounds__(256)
void pre_xbase_mfma_kernel(const float* __restrict__ item_w,
                           const short* __restrict__ W1hi,
                           const short* __restrict__ W1lo,
                           float* __restrict__ xbase) {
  const int lane = threadIdx.x & 63, w = threadIdx.x >> 6;
  const int l15 = lane & 15, lg4 = lane >> 4;
  short8 bh[8], bl[8];                     // [kb*4+nb]
#pragma unroll
  for (int q = 0; q < 8; ++q) {
    bh[q] = *(const short8*)(W1hi + (q * 64 + lane) * 8);
    bl[q] = *(const short8*)(W1lo + (q * 64 + lane) * 8);
  }
  const int wid = blockIdx.x * 4 + w;
  const int nw = gridDim.x * 4;
  for (int tile = wid; tile < 3125; tile += nw) {
    const long r0 = (long)tile * 16;
    const float* ap = item_w + (r0 + l15) * 64 + lg4 * 8;
    short8 ah[2], al[2];
#pragma unroll
    for (int kb = 0; kb < 2; ++kb) {
      const float4 a = *(const float4*)(ap + kb * 32);
      const float4 b = *(const float4*)(ap + kb * 32 + 4);
      float v[8] = {a.x, a.y, a.z, a.w, b.x, b.y, b.z, b.w};
      short8 hi, lo;
#pragma unroll
      for (int e = 0; e < 8; ++e) {
        short h = bf16rne(v[e]);
        hi[e] = h;
        lo[e] = bf16rne(v[e] - bf16tof(h));
      }
      ah[kb] = hi;
      al[kb] = lo;
    }
#pragma unroll
    for (int nb = 0; nb < 4; ++nb) {
      f32x4 acc = {0.0f, 0.0f, 0.0f, 0.0f};
      acc = __builtin_amdgcn_mfma_f32_16x16x32_bf16(ah[0], bh[0 * 4 + nb], acc, 0, 0, 0);
      acc = __builtin_amdgcn_mfma_f32_16x16x32_bf16(ah[1], bh[1 * 4 + nb], acc, 0, 0, 0);
      acc = __builtin_amdgcn_mfma_f32_16x16x32_bf16(ah[0], bl[0 * 4 + nb], acc, 0, 0, 0);
      acc = __builtin_amdgcn_mfma_f32_16x16x32_bf16(ah[1], bl[1 * 4 + nb], acc, 0, 0, 0);
      acc = __builtin_amdgcn_mfma_f32_16x16x32_bf16(al[0], bh[0 * 4 + nb], acc, 0, 0, 0);
      acc = __builtin_amdgcn_mfma_f32_16x16x32_bf16(al[1], bh[1 * 4 + nb], acc, 0, 0, 0);
#pragma unroll
      for (int r = 0; r < 4; ++r)
        xbase[(r0 + lg4 * 4 + r) * 64 + nb * 16 + l15] = acc[r];
    }
  }
}

// ---------------------------------------------------------------------------
// K4: uA1buf[idx] = user_w[aUid[idx]] @ A1w[64:128] + A1b.  64 rows/block.
// ---------------------------------------------------------------------------
__global__ __launch_bounds__(256, 2)
void uA1_kernel(const float* __restrict__ user_w,
                const float* __restrict__ A1w, const float* __restrict__ A1b,
                const int* __restrict__ idxsrc, const int* __restrict__ nActp,
                float* __restrict__ uA1buf) {
  const int tid = threadIdx.x, lane = tid & 63, w = tid >> 6;
  const int i0 = blockIdx.x * 64;
  const int nA = nActp[0];
  if (i0 >= nA) return;
  __shared__ float sW[64][64], sU[64][64];
  __shared__ float sb[64];
  __shared__ int sUid[64];
  for (int i = tid; i < 4096; i += 256) sW[i >> 6][i & 63] = A1w[4096 + i];
  if (tid < 64) {
    sb[tid] = A1b[tid];
    sUid[tid] = (i0 + tid < nA) ? idxsrc[i0 + tid] : 0;
  }
  __syncthreads();
  for (int i = tid; i < 4096; i += 256) {
    int r = i >> 6, c = i & 63;
    sU[r][c] = user_w[(long)sUid[r] * 64 + c];
  }
  __syncthreads();
  float acc[16];
#pragma unroll
  for (int r = 0; r < 16; ++r) acc[r] = sb[lane];
  for (int k = 0; k < 64; k += 4) {
    float wv0 = sW[k][lane], wv1 = sW[k + 1][lane];
    float wv2 = sW[k + 2][lane], wv3 = sW[k + 3][lane];
#pragma unroll
    for (int r = 0; r < 16; ++r) {
      const float4 xv = *(const float4*)(&sU[w * 16 + r][k]);
      acc[r] = fmaf(xv.x, wv0, acc[r]);
      acc[r] = fmaf(xv.y, wv1, acc[r]);
      acc[r] = fmaf(xv.z, wv2, acc[r]);
      acc[r] = fmaf(xv.w, wv3, acc[r]);
    }
  }
#pragma unroll
  for (int r = 0; r < 16; ++r) {
    int row = i0 + w * 16 + r;
    if (row < nA) uA1buf[(long)row * 64 + lane] = acc[r];
  }
}

// ---------------------------------------------------------------------------
// K5: CORE — wave-per-instance attention, MFMA bf16 logits (round-8 body).
// Grid NT/8 = 2112 blocks x 8 waves => every wave handles AT MOST ONE
// instance (kills the 2-instance tail). Block-level early exit pre-staging.
// ---------------------------------------------------------------------------
__global__ __launch_bounds__(512, 8)
void core_mfma_kernel(const float* __restrict__ xbase,
                      const float* __restrict__ RW1g,
                      const float* __restrict__ uA1buf,
                      const short* __restrict__ Bimg1,
                      const short* __restrict__ Bimg2,
                      const float* __restrict__ A2b,
                      const float* __restrict__ A3w,
                      const int* __restrict__ item_hist,
                      const int* __restrict__ rating_hist,
                      const void* __restrict__ item_mask,
                      const int* __restrict__ flagp,
                      const int* __restrict__ aUid,
                      const int* __restrict__ nActp,
                      float* __restrict__ hvecbuf) {
  __shared__ __align__(16) short sB1[4096], sB2[4096];   // 16KB images
  __shared__ __align__(16) char smem[8][3072];           // 24KB wave scratch
  const int tid = threadIdx.x, lane = tid & 63, w = tid >> 6;
  const int nA = nActp[0];
  if (blockIdx.x * 8 >= nA) return;        // uniform: whole block exits

  short* h1w = (short*)(smem[w]);          // [16][80] bf16
  float* lgw = (float*)(smem[w] + 2560);   // [64] logits
  int* cw = (int*)(smem[w] + 2816);        // [64] packed (item<<3)|rating

  ((int4*)sB1)[tid] = ((const int4*)Bimg1)[tid];   // 512 * 16B = 8KB each
  ((int4*)sB2)[tid] = ((const int4*)Bimg2)[tid];
  __syncthreads();   // the only block-wide barrier

  const int idx = blockIdx.x * 8 + w;
  if (idx >= nA) return;                   // wave-level; no barriers follow

  const int mode = flagp[0];
  const float a2bv = A2b[lane];
  const float a3v = A3w[lane];
  const int l15 = lane & 15;
  const int lg4 = lane >> 4;

#define B1F(q) (*(const short8*)(sB1 + ((q) * 64 + lane) * 8))
#define B2F(q) (*(const short8*)(sB2 + ((q) * 64 + lane) * 8))

  const long uid = aUid[idx];

  // ---- compact item history (lane covers LI=64) ----
  const long mbase = uid * 64;
  bool mk = mread(item_mask, mbase + lane, mode);
  unsigned long long bal = __ballot(mk);
  const int nact = (int)__popcll(bal);
  int pos = (int)__popcll(bal & ((1ull << lane) - 1ull));
  if (mk) cw[pos] = (item_hist[mbase + lane] << 3) | rating_hist[mbase + lane];
  const float uA1v = uA1buf[(long)idx * 64 + lane];
  wave_fence();

  // ---- logits via MFMA, 16-row chunks ----
  const int ng = (nact + 15) >> 4;
  for (int mc = 0; mc < ng; ++mc) {
    wave_fence();  // prior chunk's H1 reads done before overwrite
    int row = mc * 16 + l15;
    if (row >= nact) row = nact - 1;
    const int p = cw[row];
    const long it = p >> 3;
    const int rt = p & 7;
    short8 xa[2];
#pragma unroll
    for (int kb = 0; kb < 2; ++kb) {
      const int koff = kb * 32 + lg4 * 8;
      const float* xp = xbase + it * 64 + koff;
      const float* rp = RW1g + rt * 64 + koff;
      const float4 a = *(const float4*)xp;
      const float4 b = *(const float4*)(xp + 4);
      const float4 c = *(const float4*)rp;
      const float4 d = *(const float4*)(rp + 4);
      short8 f;
      f[0] = bf16rne(fmaxf(a.x + c.x, 0.0f));
      f[1] = bf16rne(fmaxf(a.y + c.y, 0.0f));
      f[2] = bf16rne(fmaxf(a.z + c.z, 0.0f));
      f[3] = bf16rne(fmaxf(a.w + c.w, 0.0f));
      f[4] = bf16rne(fmaxf(b.x + d.x, 0.0f));
      f[5] = bf16rne(fmaxf(b.y + d.y, 0.0f));
      f[6] = bf16rne(fmaxf(b.z + d.z, 0.0f));
      f[7] = bf16rne(fmaxf(b.w + d.w, 0.0f));
      xa[kb] = f;
    }
    // att1: H1 = relu(X @ A1a + uA1)
#pragma unroll
    for (int nb = 0; nb < 4; ++nb) {
      const float ui = __shfl(uA1v, nb * 16 + l15);
      f32x4 acc = {ui, ui, ui, ui};
      acc = __builtin_amdgcn_mfma_f32_16x16x32_bf16(xa[0], B1F(0 * 4 + nb), acc, 0, 0, 0);
      acc = __builtin_amdgcn_mfma_f32_16x16x32_bf16(xa[1], B1F(1 * 4 + nb), acc, 0, 0, 0);
#pragma unroll
      for (int r = 0; r < 4; ++r)
        h1w[(lg4 * 4 + r) * 80 + nb * 16 + l15] = bf16rne(fmaxf(acc[r], 0.0f));
    }
    wave_fence();
    // att2 + logit
    short8 ha[2];
    ha[0] = *(const short8*)(h1w + l15 * 80 + lg4 * 8);
    ha[1] = *(const short8*)(h1w + l15 * 80 + 32 + lg4 * 8);
    float t0 = 0.0f, t1 = 0.0f, t2 = 0.0f, t3 = 0.0f;
#pragma unroll
    for (int nb = 0; nb < 4; ++nb) {
      const float b2 = __shfl(a2bv, nb * 16 + l15);
      f32x4 acc = {b2, b2, b2, b2};
      acc = __builtin_amdgcn_mfma_f32_16x16x32_bf16(ha[0], B2F(0 * 4 + nb), acc, 0, 0, 0);
      acc = __builtin_amdgcn_mfma_f32_16x16x32_bf16(ha[1], B2F(1 * 4 + nb), acc, 0, 0, 0);
      const float a3c = __shfl(a3v, nb * 16 + l15);
      t0 = fmaf(fmaxf(acc[0], 0.0f), a3c, t0);
      t1 = fmaf(fmaxf(acc[1], 0.0f), a3c, t1);
      t2 = fmaf(fmaxf(acc[2], 0.0f), a3c, t2);
      t3 = fmaf(fmaxf(acc[3], 0.0f), a3c, t3);
    }
    t0 = rsum16(t0); t1 = rsum16(t1); t2 = rsum16(t2); t3 = rsum16(t3);
    if (l15 == 0) {
      const int jb = mc * 16 + lg4 * 4;
      lgw[jb + 0] = t0;
      lgw[jb + 1] = t1;
      lgw[jb + 2] = t2;
      lgw[jb + 3] = t3;
    }
  }
  wave_fence();

  // ---- softmax over lanes ----
  const bool valid = (lane < nact);
  float lv = valid ? lgw[lane] : -1e30f;
  float mx = wmax(lv);
  float e = valid ? __expf(lv - mx) : 0.0f;
  float s = wsum(e);
  const float alpha = e / s;

  // ---- hI = sum_j alpha_j * x_j (exact f32 re-gather, unrolled x4) ----
  float h0 = 0.0f, hA = 0.0f, hB = 0.0f, hC = 0.0f;
  int j = 0;
  for (; j + 3 < nact; j += 4) {
    const int p0 = cw[j], p1 = cw[j + 1], p2 = cw[j + 2], p3 = cw[j + 3];
    const float a0 = __shfl(alpha, j), a1 = __shfl(alpha, j + 1);
    const float a2 = __shfl(alpha, j + 2), a3 = __shfl(alpha, j + 3);
    const float x0 = xbase[(long)(p0 >> 3) * 64 + lane] + RW1g[(p0 & 7) * 64 + lane];
    const float x1 = xbase[(long)(p1 >> 3) * 64 + lane] + RW1g[(p1 & 7) * 64 + lane];
    const float x2 = xbase[(long)(p2 >> 3) * 64 + lane] + RW1g[(p2 & 7) * 64 + lane];
    const float x3 = xbase[(long)(p3 >> 3) * 64 + lane] + RW1g[(p3 & 7) * 64 + lane];
    h0 = fmaf(a0, fmaxf(x0, 0.0f), h0);
    hA = fmaf(a1, fmaxf(x1, 0.0f), hA);
    hB = fmaf(a2, fmaxf(x2, 0.0f), hB);
    hC = fmaf(a3, fmaxf(x3, 0.0f), hC);
  }
  for (; j < nact; ++j) {
    const int p = cw[j];
    const float aj = __shfl(alpha, j);
    const float xv = xbase[(long)(p >> 3) * 64 + lane] + RW1g[(p & 7) * 64 + lane];
    h0 = fmaf(aj, fmaxf(xv, 0.0f), h0);
  }
  hvecbuf[(long)idx * 64 + lane] = (h0 + hA) + (hB + hC);
#undef B1F
#undef B2F
}

// ---------------------------------------------------------------------------
// K6: fused hI2 + final, weight-amortized: W2 and W3 both LDS-resident,
// 4 row-groups of 32 per block (weight traffic 34MB -> 6MB).
// ---------------------------------------------------------------------------
__global__ __launch_bounds__(256, 2)
void hI2final_kernel(const float* __restrict__ hvecbuf,
                     const float* __restrict__ user_w,
                     const float* __restrict__ W2w, const float* __restrict__ W2b,
                     const float* __restrict__ W3w, const float* __restrict__ W3b,
                     const int* __restrict__ list, const int* __restrict__ aUid,
                     const int* __restrict__ nActp, float* __restrict__ hIbuf) {
  const int tid = threadIdx.x, lane = tid & 63, w = tid >> 6;
  const int nA = nActp[0];
  if (blockIdx.x * 128 >= nA) return;
  __shared__ float sW2[64][64];    // 16KB
  __shared__ float sW3[128][64];   // 32KB
  __shared__ float sX[32][128];    // 16KB: cols 0:64 = u, 64:128 = hvec/hI2
  __shared__ float sb2[64], sb3[64];
  __shared__ int sUid[32], sInst[32];
  for (int i = tid; i < 4096; i += 256) sW2[i >> 6][i & 63] = W2w[i];
  for (int i = tid; i < 8192; i += 256) sW3[i >> 6][i & 63] = W3w[i];
  if (tid < 64) { sb2[tid] = W2b[tid]; sb3[tid] = W3b[tid]; }

  for (int g2 = 0; g2 < 4; ++g2) {
    const int i0 = (blockIdx.x * 4 + g2) * 32;
    if (i0 >= nA) break;                  // uniform across block
    __syncthreads();  // weights staged (g2=0) / prior group fully consumed
    if (tid < 32) {
      bool ok = (i0 + tid) < nA;
      sUid[tid] = ok ? aUid[i0 + tid] : 0;
      sInst[tid] = ok ? list[i0 + tid] : 0;
    }
    __syncthreads();
    for (int i = tid; i < 2048; i += 256) {
      int r = i >> 6, c = i & 63;
      sX[r][64 + c] = (i0 + r < nA) ? hvecbuf[(long)(i0 + r) * 64 + c] : 0.0f;
      sX[r][c] = user_w[(long)sUid[r] * 64 + c];
    }
    __syncthreads();

    float acc[8];
    // stage A: hI2 = relu(hvec @ W2 + b2) -> sX[r][64:]  (own-wave rows only)
    {
      const float bv = sb2[lane];
#pragma unroll
      for (int r = 0; r < 8; ++r) acc[r] = bv;
      for (int k = 0; k < 64; k += 4) {
        float wv0 = sW2[k][lane], wv1 = sW2[k + 1][lane];
        float wv2 = sW2[k + 2][lane], wv3 = sW2[k + 3][lane];
#pragma unroll
        for (int r = 0; r < 8; ++r) {
          const float4 xv = *(const float4*)(&sX[w * 8 + r][64 + k]);
          acc[r] = fmaf(xv.x, wv0, acc[r]);
          acc[r] = fmaf(xv.y, wv1, acc[r]);
          acc[r] = fmaf(xv.z, wv2, acc[r]);
          acc[r] = fmaf(xv.w, wv3, acc[r]);
        }
      }
#pragma unroll
      for (int r = 0; r < 8; ++r) sX[w * 8 + r][64 + lane] = fmaxf(acc[r], 0.0f);
    }
    // stage B: out = relu([u ; hI2] @ W3 + b3)  (own-wave rows only)
    {
      const float bv = sb3[lane];
#pragma unroll
      for (int r = 0; r < 8; ++r) acc[r] = bv;
      for (int k = 0; k < 128; k += 4) {
        float wv0 = sW3[k][lane], wv1 = sW3[k + 1][lane];
        float wv2 = sW3[k + 2][lane], wv3 = sW3[k + 3][lane];
#pragma unroll
        for (int r = 0; r < 8; ++r) {
          const float4 xv = *(const float4*)(&sX[w * 8 + r][k]);
          acc[r] = fmaf(xv.x, wv0, acc[r]);
          acc[r] = fmaf(xv.y, wv1, acc[r]);
          acc[r] = fmaf(xv.z, wv2, acc[r]);
          acc[r] = fmaf(xv.w, wv3, acc[r]);
        }
      }
#pragma unroll
      for (int r = 0; r < 8; ++r) {
        int row = i0 + w * 8 + r;
        if (row < nA)
          hIbuf[(long)sInst[w * 8 + r] * 64 + lane] = fmaxf(acc[r], 0.0f);
      }
    }
  }
}

// ---------------------------------------------------------------------------
// K7: fully fused social phase — one wave per batch element b. B-images
// built in-kernel from s_att1/s_att2 (no global prepack).
// ---------------------------------------------------------------------------
__global__ __launch_bounds__(256, 8)
void social_fused_kernel(const float* __restrict__ hIbuf,
                         const float* __restrict__ user_w,
                         const float* __restrict__ S1w,   // s_att1_w [128][64]
                         const float* __restrict__ S1b,
                         const float* __restrict__ S2w,   // s_att2_w [64][64]
                         const float* __restrict__ S2b,
                         const float* __restrict__ S3w,
                         const float* __restrict__ L1w, const float* __restrict__ L1b,
                         const float* __restrict__ L2w, const float* __restrict__ L2b,
                         const float* __restrict__ L3w, const float* __restrict__ L3b,
                         const int* __restrict__ nodes,
                         const void* __restrict__ social_mask,
                         const int* __restrict__ flagp,
                         float* __restrict__ out) {
  __shared__ __align__(16) short sB1[4096], sB2[4096];   // 16KB images
  __shared__ __align__(16) char smem[4][3584];           // 14KB wave scratch
  const int tid = threadIdx.x, lane = tid & 63, w = tid >> 6;
  short* h1w = (short*)(smem[w]);          // [16][80] bf16
  float* lgw = (float*)(smem[w] + 2560);   // [32] logits
  int* cw = (int*)(smem[w] + 2816);        // [32] neighbor slots
  float* vA = (float*)(smem[w] + 3072);    // [64]
  float* vB = (float*)(smem[w] + 3328);    // [64]

  // build B-fragment images directly from global weights (L2-hot)
  for (int i = tid; i < 4096; i += 256) {
    int e = i & 7, g = i >> 3;
    int l = g & 63, q = g >> 6;
    int kb = q >> 2, nb = q & 3;
    int k = kb * 32 + ((l >> 4) & 3) * 8 + e;
    int col = nb * 16 + (l & 15);
    sB1[i] = bf16rne(S1w[k * 64 + col]);
    sB2[i] = bf16rne(S2w[k * 64 + col]);
  }
  __syncthreads();

  const int mode = flagp[0];
  const int l15 = lane & 15;
  const int lg4 = lane >> 4;
  const int b = blockIdx.x * 4 + w;        // grid 128*4 = 512 exactly
  const long uid = nodes[b];

  bool m = (lane < LSS) ? mread(social_mask, uid * LSS + lane, mode) : false;
  unsigned long long bal = __ballot(m);
  const int nval = (int)__popcll(bal);
  int pos = (int)__popcll(bal & ((1ull << lane) - 1ull));
  if (m) cw[pos] = lane;

  // inline uA1S = u @ S1w[64:128] + S1b
  const float uv = user_w[uid * 64 + lane];
  float uA1v = S1b[lane];
#pragma unroll 8
  for (int k = 0; k < 64; ++k)
    uA1v = fmaf(__shfl(uv, k), S1w[(64 + k) * 64 + lane], uA1v);
  const float a2bv = S2b[lane];
  const float a3v = S3w[lane];
  wave_fence();

  const long hbase = 512L + (long)b * 32;
  const int ng = (nval + 15) >> 4;
  for (int mc = 0; mc < ng; ++mc) {
    wave_fence();
    int row = mc * 16 + l15;
    if (row >= nval) row = nval - 1;
    const long hrow = hbase + cw[row];
    short8 xa[2];
#pragma unroll
    for (int kb = 0; kb < 2; ++kb) {
      const float* xp = hIbuf + hrow * 64 + kb * 32 + lg4 * 8;
      const float4 a = *(const float4*)xp;
      const float4 bb = *(const float4*)(xp + 4);
      short8 f;
      f[0] = bf16rne(a.x);  f[1] = bf16rne(a.y);
      f[2] = bf16rne(a.z);  f[3] = bf16rne(a.w);
      f[4] = bf16rne(bb.x); f[5] = bf16rne(bb.y);
      f[6] = bf16rne(bb.z); f[7] = bf16rne(bb.w);
      xa[kb] = f;
    }
#pragma unroll
    for (int nb = 0; nb < 4; ++nb) {
      const float ui = __shfl(uA1v, nb * 16 + l15);
      f32x4 acc = {ui, ui, ui, ui};
      acc = __builtin_amdgcn_mfma_f32_16x16x32_bf16(
          xa[0], *(const short8*)(sB1 + ((0 * 4 + nb) * 64 + lane) * 8), acc, 0, 0, 0);
      acc = __builtin_amdgcn_mfma_f32_16x16x32_bf16(
          xa[1], *(const short8*)(sB1 + ((1 * 4 + nb) * 64 + lane) * 8), acc, 0, 0, 0);
#pragma unroll
      for (int r = 0; r < 4; ++r)
        h1w[(lg4 * 4 + r) * 80 + nb * 16 + l15] = bf16rne(fmaxf(acc[r], 0.0f));
    }
    wave_fence();
    short8 ha[2];
    ha[0] = *(const short8*)(h1w + l15 * 80 + lg4 * 8);
    ha[1] = *(const short8*)(h1w + l15 * 80 + 32 + lg4 * 8);
    float t0 = 0.0f, t1 = 0.0f, t2 = 0.0f, t3 = 0.0f;
#pragma unroll
    for (int nb = 0; nb < 4; ++nb) {
      const float b2 = __shfl(a2bv, nb * 16 + l15);
      f32x4 acc = {b2, b2, b2, b2};
      acc = __builtin_amdgcn_mfma_f32_16x16x32_bf16(
          ha[0], *(const short8*)(sB2 + ((0 * 4 + nb) * 64 + lane) * 8), acc, 0, 0, 0);
      acc = __builtin_amdgcn_mfma_f32_16x16x32_bf16(
          ha[1], *(const short8*)(sB2 + ((1 * 4 + nb) * 64 + lane) * 8), acc, 0, 0, 0);
      const float a3c = __shfl(a3v, nb * 16 + l15);
      t0 = fmaf(fmaxf(acc[0], 0.0f), a3c, t0);
      t1 = fmaf(fmaxf(acc[1], 0.0f), a3c, t1);
      t2 = fmaf(fmaxf(acc[2], 0.0f), a3c, t2);
      t3 = fmaf(fmaxf(acc[3], 0.0f), a3c, t3);
    }
    t0 = rsum16(t0); t1 = rsum16(t1); t2 = rsum16(t2); t3 = rsum16(t3);
    if (l15 == 0) {
      const int jb = mc * 16 + lg4 * 4;
      lgw[jb + 0] = t0;
      lgw[jb + 1] = t1;
      lgw[jb + 2] = t2;
      lgw[jb + 3] = t3;
    }
  }
  wave_fence();

  const bool valid = (lane < nval);
  float lv = valid ? lgw[lane] : -1e30f;
  float mx = wmax(lv);
  float e = valid ? __expf(lv - mx) : 0.0f;
  float s = wsum(e);
  const float beta = e / s;

  float hs = 0.0f;
  for (int j = 0; j < nval; ++j) {
    const float bj = __shfl(beta, j);
    hs = fmaf(bj, hIbuf[(hbase + cw[j]) * 64 + lane], hs);
  }

  // ---- tail matvecs ----
  vA[lane] = hs;
  wave_fence();
  float acc = L1b[lane];
#pragma unroll 8
  for (int k = 0; k < 64; ++k) acc = fmaf(vA[k], L1w[k * 64 + lane], acc);
  const float vecB = fmaxf(acc, 0.0f);
  const float selfv = hIbuf[(long)b * 64 + lane];
  wave_fence();
  vA[lane] = selfv;
  vB[lane] = vecB;
  wave_fence();
  acc = L2b[lane];
#pragma unroll 8
  for (int k = 0; k < 64; ++k) acc = fmaf(vA[k], L2w[k * 64 + lane], acc);
#pragma unroll 8
  for (int k = 0; k < 64; ++k) acc = fmaf(vB[k], L2w[(64 + k) * 64 + lane], acc);
  const float fv = fmaxf(acc, 0.0f);
  wave_fence();
  vA[lane] = fv;
  wave_fence();
  acc = L3b[lane];
#pragma unroll 8
  for (int k = 0; k < 64; ++k) acc = fmaf(vA[k], L3w[k * 64 + lane], acc);
  out[(long)b * 64 + lane] = fmaxf(acc, 0.0f);
}

// ---------------------------------------------------------------------------
extern "C" void kernel_launch(void* const* d_in, const int* in_sizes, int n_in,
                              void* d_out, int out_size, void* d_ws, size_t ws_size,
                              hipStream_t stream) {
  const float* user_w   = (const float*)d_in[0];
  const float* item_w   = (const float*)d_in[1];
  const float* rating_w = (const float*)d_in[2];
  const float* i_ln1_w  = (const float*)d_in[3];
  const float* i_ln1_b  = (const float*)d_in[4];
  const float* i_ln2_w  = (const float*)d_in[5];
  const float* i_ln2_b  = (const float*)d_in[6];
  const float* i_ln3_w  = (const float*)d_in[7];
  const float* i_ln3_b  = (const float*)d_in[8];
  const float* i_att1_w = (const float*)d_in[9];
  const float* i_att1_b = (const float*)d_in[10];
  const float* i_att2_w = (const float*)d_in[11];
  const float* i_att2_b = (const float*)d_in[12];
  const float* i_att3_w = (const float*)d_in[13];
  const float* i_att3_b = (const float*)d_in[14];
  const float* s_ln1_w  = (const float*)d_in[15];
  const float* s_ln1_b  = (const float*)d_in[16];
  const float* s_ln2_w  = (const float*)d_in[17];
  const float* s_ln2_b  = (const float*)d_in[18];
  const float* s_ln3_w  = (const float*)d_in[19];
  const float* s_ln3_b  = (const float*)d_in[20];
  const float* s_att1_w = (const float*)d_in[21];
  const float* s_att1_b = (const float*)d_in[22];
  const float* s_att2_w = (const float*)d_in[23];
  const float* s_att2_b = (const float*)d_in[24];
  const float* s_att3_w = (const float*)d_in[25];
  const float* s_att3_b = (const float*)d_in[26];
  const int*  nodes       = (const int*)d_in[27];
  const int*  social_hist = (const int*)d_in[28];
  const void* social_mask = d_in[29];
  const int*  item_hist   = (const int*)d_in[30];
  const int*  rating_hist = (const int*)d_in[31];
  const void* item_mask   = d_in[32];

  // workspace layout (bytes) — total 21,604,096 (proven cap; do not exceed).
  char* ws = (char*)d_ws;
  int*   flag    = (int*)(ws + 0);          // 256
  int*   counter = (int*)(ws + 256);        // 256
  int*   list    = (int*)(ws + 512);        // NT*4 = 67584
  int*   aUid    = (int*)(ws + 68096);      // 67584
  float* uA1buf  = (float*)(ws + 135680);   // NT*64*4 = 4325376
  float* hvecbuf = (float*)(ws + 4461056);  // 4325376
  float* hIbuf   = hvecbuf;                 // alias: hvec dead before K6 write
  short* W1hi    = (short*)(ws + 4461056);  // 8192  (alias hvecbuf[0:2048])
  short* W1lo    = (short*)(ws + 4469248);  // 8192  (alias hvecbuf[2048:4096])
  float* xbase   = (float*)(ws + 8786432);  // 50000*64*4 = 12800000
  float* RW1g    = (float*)(ws + 21586432); // 1280
  short* Bimg1   = (short*)(ws + 21587712); // 8192
  short* Bimg2   = (short*)(ws + 21595904); // 8192

  hipMemsetAsync(counter, 0, 4, stream);
  setup_kernel<<<3 + NT / 256, 256, 0, stream>>>(
      (const unsigned int*)social_mask, flag,
      rating_w, i_ln1_w, i_ln1_b, RW1g,
      i_att1_w, i_att2_w, Bimg1, Bimg2, W1hi, W1lo,
      nodes, social_hist, counter, list, aUid);
  pre_xbase_mfma_kernel<<<512, 256, 0, stream>>>(item_w, W1hi, W1lo, xbase);
  uA1_kernel<<<NT / 64, 256, 0, stream>>>(user_w, i_att1_w, i_att1_b,
                                          aUid, counter, uA1buf);
  core_mfma_kernel<<<NT / 8, 512, 0, stream>>>(
      xbase, RW1g, uA1buf, Bimg1, Bimg2, i_att2_b, i_att3_w,
      item_hist, rating_hist, item_mask, flag, aUid, counter, hvecbuf);
  hI2final_kernel<<<NT / 128, 256, 0, stream>>>(
      hvecbuf, user_w, i_ln2_w, i_ln2_b, i_ln3_w, i_ln3_b,
      list, aUid, counter, hIbuf);
  social_fused_kernel<<<BB / 4, 256, 0, stream>>>(
      hIbuf, user_w, s_att1_w, s_att1_b, s_att2_w, s_att2_b, s_att3_w,
      s_ln1_w, s_ln1_b, s_ln2_w, s_ln2_b, s_ln3_w, s_ln3_b,
      nodes, social_mask, flag, (float*)d_out);
}

// Round 12
// 115.073 us; speedup vs baseline: 1.2296x; 1.2296x over previous
//
#include <hip/hip_runtime.h>
#include <math.h>

// ---------------------------------------------------------------------------
// Aggre_social on MI355X — round 12: revert hI2final to the round-8 high-
// parallelism form (528 blocks; weight re-reads are L2-free — round-11's
// amortization starved the GPU); hIbuf moved to the dead uA1buf region
// (removes the latent hvecbuf alias race). Core/setup/social = round 11.
// ws layout cap unchanged (21,604,096 B).
// Sizes: NU=NI=50000, NR=5, D=64, B=512, LS=32, LI=64.
// ---------------------------------------------------------------------------

#define NII 50000
#define BB 512
#define LSS 32
#define NT 16896   // 512 self + 16384 neighbor instances

typedef short short8 __attribute__((ext_vector_type(8)));
typedef float f32x4 __attribute__((ext_vector_type(4)));

static __device__ __forceinline__ bool mread(const void* p, long i, int mode) {
  if (mode == 0) return ((const int*)p)[i] != 0;       // int32 storage
  if (mode == 2) return ((const float*)p)[i] != 0.0f;  // f32 storage
  return ((const unsigned char*)p)[i] != 0;            // byte storage
}

static __device__ __forceinline__ float wsum(float v) {
#pragma unroll
  for (int s = 1; s < 64; s <<= 1) v += __shfl_xor(v, s);
  return v;
}
static __device__ __forceinline__ float wmax(float v) {
#pragma unroll
  for (int s = 1; s < 64; s <<= 1) v = fmaxf(v, __shfl_xor(v, s));
  return v;
}
static __device__ __forceinline__ float rsum16(float v) {
#pragma unroll
  for (int s = 1; s < 16; s <<= 1) v += __shfl_xor(v, s);
  return v;
}

// f32 -> bf16 (round-to-nearest-even), as raw short.
static __device__ __forceinline__ short bf16rne(float f) {
  unsigned u = __float_as_uint(f);
  u = (u + 0x7FFFu + ((u >> 16) & 1u)) >> 16;
  return (short)u;
}
static __device__ __forceinline__ float bf16tof(short h) {
  return __uint_as_float(((unsigned)(unsigned short)h) << 16);
}

// Intra-wave LDS write->read fence.
static __device__ __forceinline__ void wave_fence() {
  asm volatile("s_waitcnt lgkmcnt(0)" ::: "memory");
  __builtin_amdgcn_sched_barrier(0);
}

// ---------------------------------------------------------------------------
// K0: fused setup. block 0: mask-format detect; block 1: RW1g matvec;
// block 2: prepack item-att B-images + W1 hi/lo split; blocks 3..68: build
// active instance list (local mask-format detect per block).   <<<69,256>>>
// ---------------------------------------------------------------------------
__global__ void setup_kernel(const unsigned int* __restrict__ sm,
                             int* __restrict__ flag,
                             const float* __restrict__ rating_w,
                             const float* __restrict__ w1,
                             const float* __restrict__ b1,
                             float* __restrict__ RW1g,
                             const float* __restrict__ A1w,
                             const float* __restrict__ A2w,
                             short* __restrict__ B1,
                             short* __restrict__ B2,
                             short* __restrict__ W1hi,
                             short* __restrict__ W1lo,
                             const int* __restrict__ nodes,
                             const int* __restrict__ social_hist,
                             int* __restrict__ counter,
                             int* __restrict__ list,
                             int* __restrict__ aUid) {
  const int tid = threadIdx.x;
  if (blockIdx.x == 0) {
    __shared__ int notInt, notFloat;
    if (tid == 0) { notInt = 0; notFloat = 0; }
    __syncthreads();
    int ni = 0, nf = 0;
    for (int i = tid; i < 4096; i += 256) {
      unsigned int x = sm[i];
      if (x > 1u) ni = 1;
      if (x != 0u && x != 0x3F800000u) nf = 1;
    }
    if (ni) atomicOr(&notInt, 1);
    if (nf) atomicOr(&notFloat, 1);
    __syncthreads();
    if (tid == 0) flag[0] = notInt ? (notFloat ? 1 : 2) : 0;
  } else if (blockIdx.x == 1) {
    for (int t = tid; t < 320; t += 256) {
      const int r = t >> 6, c = t & 63;
      float acc = b1[c];
      for (int k = 0; k < 64; ++k)
        acc = fmaf(rating_w[r * 64 + k], w1[(64 + k) * 64 + c], acc);
      RW1g[r * 64 + c] = acc;
    }
  } else if (blockIdx.x == 2) {
    for (int idx = tid; idx < 4096; idx += 256) {
      int e = idx & 7, g = idx >> 3;
      int l = g & 63, q = g >> 6;        // q = kb*4+nb
      int kb = q >> 2, nb = q & 3;
      int k = kb * 32 + ((l >> 4) & 3) * 8 + e;
      int col = nb * 16 + (l & 15);
      B1[idx] = bf16rne(A1w[k * 64 + col]);
      B2[idx] = bf16rne(A2w[k * 64 + col]);
      float a = w1[k * 64 + col];
      short h = bf16rne(a);
      W1hi[idx] = h;
      W1lo[idx] = bf16rne(a - bf16tof(h));
    }
  } else {
    // build active list; per-block local mask-format detect (no dependency
    // on block 0 — blocks may run in any order).
    __shared__ int nI, nF;
    if (tid == 0) { nI = 0; nF = 0; }
    __syncthreads();
    int ni = 0, nf = 0;
    for (int i = tid; i < 4096; i += 256) {
      unsigned int x = sm[i];
      if (x > 1u) ni = 1;
      if (x != 0u && x != 0x3F800000u) nf = 1;
    }
    if (ni) atomicOr(&nI, 1);
    if (nf) atomicOr(&nF, 1);
    __syncthreads();
    const int mode = nI ? (nF ? 1 : 2) : 0;
    const int t = (blockIdx.x - 3) * 256 + tid;
    if (t < NT) {
      int uid;
      bool active;
      if (t < BB) {
        active = true;
        uid = nodes[t];
      } else {
        int nb = t - BB;
        int b = nb >> 5, l = nb & 31;
        long mi = (long)nodes[b] * LSS + l;
        active = mread((const void*)sm, mi, mode);
        uid = active ? social_hist[mi] : 0;
      }
      if (active) {
        int pos = atomicAdd(counter, 1);
        list[pos] = t;
        aUid[pos] = uid;
      }
    }
  }
}

// ---------------------------------------------------------------------------
// K2: xbase[50000][64] = item_w @ W1[0:64] via split-bf16 MFMA.
// ---------------------------------------------------------------------------
__global__ __launch_bounds__(256)
void pre_xbase_mfma_kernel(const float* __restrict__ item_w,
                           const short* __restrict__ W1hi,
                           const short* __restrict__ W1lo,
                           float* __restrict__ xbase) {
  const int lane = threadIdx.x & 63, w = threadIdx.x >> 6;
  const int l15 = lane & 15, lg4 = lane >> 4;
  short8 bh[8], bl[8];                     // [kb*4+nb]
#pragma unroll
  for (int q = 0; q < 8; ++q) {
    bh[q] = *(const short8*)(W1hi + (q * 64 + lane) * 8);
    bl[q] = *(const short8*)(W1lo + (q * 64 + lane) * 8);
  }
  const int wid = blockIdx.x * 4 + w;
  const int nw = gridDim.x * 4;
  for (int tile = wid; tile < 3125; tile += nw) {
    const long r0 = (long)tile * 16;
    const float* ap = item_w + (r0 + l15) * 64 + lg4 * 8;
    short8 ah[2], al[2];
#pragma unroll
    for (int kb = 0; kb < 2; ++kb) {
      const float4 a = *(const float4*)(ap + kb * 32);
      const float4 b = *(const float4*)(ap + kb * 32 + 4);
      float v[8] = {a.x, a.y, a.z, a.w, b.x, b.y, b.z, b.w};
      short8 hi, lo;
#pragma unroll
      for (int e = 0; e < 8; ++e) {
        short h = bf16rne(v[e]);
        hi[e] = h;
        lo[e] = bf16rne(v[e] - bf16tof(h));
      }
      ah[kb] = hi;
      al[kb] = lo;
    }
#pragma unroll
    for (int nb = 0; nb < 4; ++nb) {
      f32x4 acc = {0.0f, 0.0f, 0.0f, 0.0f};
      acc = __builtin_amdgcn_mfma_f32_16x16x32_bf16(ah[0], bh[0 * 4 + nb], acc, 0, 0, 0);
      acc = __builtin_amdgcn_mfma_f32_16x16x32_bf16(ah[1], bh[1 * 4 + nb], acc, 0, 0, 0);
      acc = __builtin_amdgcn_mfma_f32_16x16x32_bf16(ah[0], bl[0 * 4 + nb], acc, 0, 0, 0);
      acc = __builtin_amdgcn_mfma_f32_16x16x32_bf16(ah[1], bl[1 * 4 + nb], acc, 0, 0, 0);
      acc = __builtin_amdgcn_mfma_f32_16x16x32_bf16(al[0], bh[0 * 4 + nb], acc, 0, 0, 0);
      acc = __builtin_amdgcn_mfma_f32_16x16x32_bf16(al[1], bh[1 * 4 + nb], acc, 0, 0, 0);
#pragma unroll
      for (int r = 0; r < 4; ++r)
        xbase[(r0 + lg4 * 4 + r) * 64 + nb * 16 + l15] = acc[r];
    }
  }
}

// ---------------------------------------------------------------------------
// K4: uA1buf[idx] = user_w[aUid[idx]] @ A1w[64:128] + A1b.  64 rows/block.
// ---------------------------------------------------------------------------
__global__ __launch_bounds__(256, 2)
void uA1_kernel(const float* __restrict__ user_w,
                const float* __restrict__ A1w, const float* __restrict__ A1b,
                const int* __restrict__ idxsrc, const int* __restrict__ nActp,
                float* __restrict__ uA1buf) {
  const int tid = threadIdx.x, lane = tid & 63, w = tid >> 6;
  const int i0 = blockIdx.x * 64;
  const int nA = nActp[0];
  if (i0 >= nA) return;
  __shared__ float sW[64][64], sU[64][64];
  __shared__ float sb[64];
  __shared__ int sUid[64];
  for (int i = tid; i < 4096; i += 256) sW[i >> 6][i & 63] = A1w[4096 + i];
  if (tid < 64) {
    sb[tid] = A1b[tid];
    sUid[tid] = (i0 + tid < nA) ? idxsrc[i0 + tid] : 0;
  }
  __syncthreads();
  for (int i = tid; i < 4096; i += 256) {
    int r = i >> 6, c = i & 63;
    sU[r][c] = user_w[(long)sUid[r] * 64 + c];
  }
  __syncthreads();
  float acc[16];
#pragma unroll
  for (int r = 0; r < 16; ++r) acc[r] = sb[lane];
  for (int k = 0; k < 64; k += 4) {
    float wv0 = sW[k][lane], wv1 = sW[k + 1][lane];
    float wv2 = sW[k + 2][lane], wv3 = sW[k + 3][lane];
#pragma unroll
    for (int r = 0; r < 16; ++r) {
      const float4 xv = *(const float4*)(&sU[w * 16 + r][k]);
      acc[r] = fmaf(xv.x, wv0, acc[r]);
      acc[r] = fmaf(xv.y, wv1, acc[r]);
      acc[r] = fmaf(xv.z, wv2, acc[r]);
      acc[r] = fmaf(xv.w, wv3, acc[r]);
    }
  }
#pragma unroll
  for (int r = 0; r < 16; ++r) {
    int row = i0 + w * 16 + r;
    if (row < nA) uA1buf[(long)row * 64 + lane] = acc[r];
  }
}

// ---------------------------------------------------------------------------
// K5: CORE — wave-per-instance attention, MFMA bf16 logits (round-8 body).
// Grid NT/8 = 2112 blocks x 8 waves => <=1 instance per wave (no tail).
// ---------------------------------------------------------------------------
__global__ __launch_bounds__(512, 8)
void core_mfma_kernel(const float* __restrict__ xbase,
                      const float* __restrict__ RW1g,
                      const float* __restrict__ uA1buf,
                      const short* __restrict__ Bimg1,
                      const short* __restrict__ Bimg2,
                      const float* __restrict__ A2b,
                      const float* __restrict__ A3w,
                      const int* __restrict__ item_hist,
                      const int* __restrict__ rating_hist,
                      const void* __restrict__ item_mask,
                      const int* __restrict__ flagp,
                      const int* __restrict__ aUid,
                      const int* __restrict__ nActp,
                      float* __restrict__ hvecbuf) {
  __shared__ __align__(16) short sB1[4096], sB2[4096];   // 16KB images
  __shared__ __align__(16) char smem[8][3072];           // 24KB wave scratch
  const int tid = threadIdx.x, lane = tid & 63, w = tid >> 6;
  const int nA = nActp[0];
  if (blockIdx.x * 8 >= nA) return;        // uniform: whole block exits

  short* h1w = (short*)(smem[w]);          // [16][80] bf16
  float* lgw = (float*)(smem[w] + 2560);   // [64] logits
  int* cw = (int*)(smem[w] + 2816);        // [64] packed (item<<3)|rating

  ((int4*)sB1)[tid] = ((const int4*)Bimg1)[tid];   // 512 * 16B = 8KB each
  ((int4*)sB2)[tid] = ((const int4*)Bimg2)[tid];
  __syncthreads();   // the only block-wide barrier

  const int idx = blockIdx.x * 8 + w;
  if (idx >= nA) return;                   // wave-level; no barriers follow

  const int mode = flagp[0];
  const float a2bv = A2b[lane];
  const float a3v = A3w[lane];
  const int l15 = lane & 15;
  const int lg4 = lane >> 4;

#define B1F(q) (*(const short8*)(sB1 + ((q) * 64 + lane) * 8))
#define B2F(q) (*(const short8*)(sB2 + ((q) * 64 + lane) * 8))

  const long uid = aUid[idx];

  // ---- compact item history (lane covers LI=64) ----
  const long mbase = uid * 64;
  bool mk = mread(item_mask, mbase + lane, mode);
  unsigned long long bal = __ballot(mk);
  const int nact = (int)__popcll(bal);
  int pos = (int)__popcll(bal & ((1ull << lane) - 1ull));
  if (mk) cw[pos] = (item_hist[mbase + lane] << 3) | rating_hist[mbase + lane];
  const float uA1v = uA1buf[(long)idx * 64 + lane];
  wave_fence();

  // ---- logits via MFMA, 16-row chunks ----
  const int ng = (nact + 15) >> 4;
  for (int mc = 0; mc < ng; ++mc) {
    wave_fence();  // prior chunk's H1 reads done before overwrite
    int row = mc * 16 + l15;
    if (row >= nact) row = nact - 1;
    const int p = cw[row];
    const long it = p >> 3;
    const int rt = p & 7;
    short8 xa[2];
#pragma unroll
    for (int kb = 0; kb < 2; ++kb) {
      const int koff = kb * 32 + lg4 * 8;
      const float* xp = xbase + it * 64 + koff;
      const float* rp = RW1g + rt * 64 + koff;
      const float4 a = *(const float4*)xp;
      const float4 b = *(const float4*)(xp + 4);
      const float4 c = *(const float4*)rp;
      const float4 d = *(const float4*)(rp + 4);
      short8 f;
      f[0] = bf16rne(fmaxf(a.x + c.x, 0.0f));
      f[1] = bf16rne(fmaxf(a.y + c.y, 0.0f));
      f[2] = bf16rne(fmaxf(a.z + c.z, 0.0f));
      f[3] = bf16rne(fmaxf(a.w + c.w, 0.0f));
      f[4] = bf16rne(fmaxf(b.x + d.x, 0.0f));
      f[5] = bf16rne(fmaxf(b.y + d.y, 0.0f));
      f[6] = bf16rne(fmaxf(b.z + d.z, 0.0f));
      f[7] = bf16rne(fmaxf(b.w + d.w, 0.0f));
      xa[kb] = f;
    }
    // att1: H1 = relu(X @ A1a + uA1)
#pragma unroll
    for (int nb = 0; nb < 4; ++nb) {
      const float ui = __shfl(uA1v, nb * 16 + l15);
      f32x4 acc = {ui, ui, ui, ui};
      acc = __builtin_amdgcn_mfma_f32_16x16x32_bf16(xa[0], B1F(0 * 4 + nb), acc, 0, 0, 0);
      acc = __builtin_amdgcn_mfma_f32_16x16x32_bf16(xa[1], B1F(1 * 4 + nb), acc, 0, 0, 0);
#pragma unroll
      for (int r = 0; r < 4; ++r)
        h1w[(lg4 * 4 + r) * 80 + nb * 16 + l15] = bf16rne(fmaxf(acc[r], 0.0f));
    }
    wave_fence();
    // att2 + logit
    short8 ha[2];
    ha[0] = *(const short8*)(h1w + l15 * 80 + lg4 * 8);
    ha[1] = *(const short8*)(h1w + l15 * 80 + 32 + lg4 * 8);
    float t0 = 0.0f, t1 = 0.0f, t2 = 0.0f, t3 = 0.0f;
#pragma unroll
    for (int nb = 0; nb < 4; ++nb) {
      const float b2 = __shfl(a2bv, nb * 16 + l15);
      f32x4 acc = {b2, b2, b2, b2};
      acc = __builtin_amdgcn_mfma_f32_16x16x32_bf16(ha[0], B2F(0 * 4 + nb), acc, 0, 0, 0);
      acc = __builtin_amdgcn_mfma_f32_16x16x32_bf16(ha[1], B2F(1 * 4 + nb), acc, 0, 0, 0);
      const float a3c = __shfl(a3v, nb * 16 + l15);
      t0 = fmaf(fmaxf(acc[0], 0.0f), a3c, t0);
      t1 = fmaf(fmaxf(acc[1], 0.0f), a3c, t1);
      t2 = fmaf(fmaxf(acc[2], 0.0f), a3c, t2);
      t3 = fmaf(fmaxf(acc[3], 0.0f), a3c, t3);
    }
    t0 = rsum16(t0); t1 = rsum16(t1); t2 = rsum16(t2); t3 = rsum16(t3);
    if (l15 == 0) {
      const int jb = mc * 16 + lg4 * 4;
      lgw[jb + 0] = t0;
      lgw[jb + 1] = t1;
      lgw[jb + 2] = t2;
      lgw[jb + 3] = t3;
    }
  }
  wave_fence();

  // ---- softmax over lanes ----
  const bool valid = (lane < nact);
  float lv = valid ? lgw[lane] : -1e30f;
  float mx = wmax(lv);
  float e = valid ? __expf(lv - mx) : 0.0f;
  float s = wsum(e);
  const float alpha = e / s;

  // ---- hI = sum_j alpha_j * x_j (exact f32 re-gather, unrolled x4) ----
  float h0 = 0.0f, hA = 0.0f, hB = 0.0f, hC = 0.0f;
  int j = 0;
  for (; j + 3 < nact; j += 4) {
    const int p0 = cw[j], p1 = cw[j + 1], p2 = cw[j + 2], p3 = cw[j + 3];
    const float a0 = __shfl(alpha, j), a1 = __shfl(alpha, j + 1);
    const float a2 = __shfl(alpha, j + 2), a3 = __shfl(alpha, j + 3);
    const float x0 = xbase[(long)(p0 >> 3) * 64 + lane] + RW1g[(p0 & 7) * 64 + lane];
    const float x1 = xbase[(long)(p1 >> 3) * 64 + lane] + RW1g[(p1 & 7) * 64 + lane];
    const float x2 = xbase[(long)(p2 >> 3) * 64 + lane] + RW1g[(p2 & 7) * 64 + lane];
    const float x3 = xbase[(long)(p3 >> 3) * 64 + lane] + RW1g[(p3 & 7) * 64 + lane];
    h0 = fmaf(a0, fmaxf(x0, 0.0f), h0);
    hA = fmaf(a1, fmaxf(x1, 0.0f), hA);
    hB = fmaf(a2, fmaxf(x2, 0.0f), hB);
    hC = fmaf(a3, fmaxf(x3, 0.0f), hC);
  }
  for (; j < nact; ++j) {
    const int p = cw[j];
    const float aj = __shfl(alpha, j);
    const float xv = xbase[(long)(p >> 3) * 64 + lane] + RW1g[(p & 7) * 64 + lane];
    h0 = fmaf(aj, fmaxf(xv, 0.0f), h0);
  }
  hvecbuf[(long)idx * 64 + lane] = (h0 + hA) + (hB + hC);
#undef B1F
#undef B2F
}

// ---------------------------------------------------------------------------
// K6: fused hI2 + final (round-8 high-parallelism form): 32 rows / block,
// NT/32 = 528 blocks; W buffer reloaded between the two stages.
// Writes hIbuf in the (dead) uA1buf region — no alias with hvecbuf.
// ---------------------------------------------------------------------------
__global__ __launch_bounds__(256, 2)
void hI2final_kernel(const float* __restrict__ hvecbuf,
                     const float* __restrict__ user_w,
                     const float* __restrict__ W2w, const float* __restrict__ W2b,
                     const float* __restrict__ W3w, const float* __restrict__ W3b,
                     const int* __restrict__ list, const int* __restrict__ aUid,
                     const int* __restrict__ nActp, float* __restrict__ hIbuf) {
  const int tid = threadIdx.x, lane = tid & 63, w = tid >> 6;
  const int i0 = blockIdx.x * 32;
  const int nA = nActp[0];
  if (i0 >= nA) return;
  __shared__ float sW[128][64];   // 32KB: W2 (rows 0..63) then W3 (0..127)
  __shared__ float sX[32][128];   // cols 0:64 = u, 64:128 = hvec then hI2
  __shared__ float sb[64];
  __shared__ int sUid[32], sInst[32];
  for (int i = tid; i < 4096; i += 256) sW[i >> 6][i & 63] = W2w[i];
  if (tid < 64) sb[tid] = W2b[tid];
  if (tid < 32) {
    bool ok = (i0 + tid) < nA;
    sUid[tid] = ok ? aUid[i0 + tid] : 0;
    sInst[tid] = ok ? list[i0 + tid] : 0;
  }
  __syncthreads();
  for (int i = tid; i < 2048; i += 256) {
    int r = i >> 6, c = i & 63;
    sX[r][64 + c] = (i0 + r < nA) ? hvecbuf[(long)(i0 + r) * 64 + c] : 0.0f;
    sX[r][c] = user_w[(long)sUid[r] * 64 + c];
  }
  __syncthreads();

  float acc[8];
  // stage A: hI2 = relu(hvec @ W2 + b2) -> sX[r][64:]
  {
    const float bv = sb[lane];
#pragma unroll
    for (int r = 0; r < 8; ++r) acc[r] = bv;
    for (int k = 0; k < 64; k += 4) {
      float wv0 = sW[k][lane], wv1 = sW[k + 1][lane];
      float wv2 = sW[k + 2][lane], wv3 = sW[k + 3][lane];
#pragma unroll
      for (int r = 0; r < 8; ++r) {
        const float4 xv = *(const float4*)(&sX[w * 8 + r][64 + k]);
        acc[r] = fmaf(xv.x, wv0, acc[r]);
        acc[r] = fmaf(xv.y, wv1, acc[r]);
        acc[r] = fmaf(xv.z, wv2, acc[r]);
        acc[r] = fmaf(xv.w, wv3, acc[r]);
      }
    }
#pragma unroll
    for (int r = 0; r < 8; ++r) sX[w * 8 + r][64 + lane] = fmaxf(acc[r], 0.0f);
  }
  __syncthreads();
  for (int i = tid; i < 8192; i += 256) sW[i >> 6][i & 63] = W3w[i];
  if (tid < 64) sb[tid] = W3b[tid];
  __syncthreads();

  // stage B: out = relu([u ; hI2] @ W3 + b3)
  {
    const float bv = sb[lane];
#pragma unroll
    for (int r = 0; r < 8; ++r) acc[r] = bv;
    for (int k = 0; k < 128; k += 4) {
      float wv0 = sW[k][lane], wv1 = sW[k + 1][lane];
      float wv2 = sW[k + 2][lane], wv3 = sW[k + 3][lane];
#pragma unroll
      for (int r = 0; r < 8; ++r) {
        const float4 xv = *(const float4*)(&sX[w * 8 + r][k]);
        acc[r] = fmaf(xv.x, wv0, acc[r]);
        acc[r] = fmaf(xv.y, wv1, acc[r]);
        acc[r] = fmaf(xv.z, wv2, acc[r]);
        acc[r] = fmaf(xv.w, wv3, acc[r]);
      }
    }
#pragma unroll
    for (int r = 0; r < 8; ++r) {
      int row = i0 + w * 8 + r;
      if (row < nA)
        hIbuf[(long)sInst[w * 8 + r] * 64 + lane] = fmaxf(acc[r], 0.0f);
    }
  }
}

// ---------------------------------------------------------------------------
// K7: fully fused social phase — one wave per batch element b. B-images
// built in-kernel from s_att1/s_att2.
// ---------------------------------------------------------------------------
__global__ __launch_bounds__(256, 8)
void social_fused_kernel(const float* __restrict__ hIbuf,
                         const float* __restrict__ user_w,
                         const float* __restrict__ S1w,   // s_att1_w [128][64]
                         const float* __restrict__ S1b,
                         const float* __restrict__ S2w,   // s_att2_w [64][64]
                         const float* __restrict__ S2b,
                         const float* __restrict__ S3w,
                         const float* __restrict__ L1w, const float* __restrict__ L1b,
                         const float* __restrict__ L2w, const float* __restrict__ L2b,
                         const float* __restrict__ L3w, const float* __restrict__ L3b,
                         const int* __restrict__ nodes,
                         const void* __restrict__ social_mask,
                         const int* __restrict__ flagp,
                         float* __restrict__ out) {
  __shared__ __align__(16) short sB1[4096], sB2[4096];   // 16KB images
  __shared__ __align__(16) char smem[4][3584];           // 14KB wave scratch
  const int tid = threadIdx.x, lane = tid & 63, w = tid >> 6;
  short* h1w = (short*)(smem[w]);          // [16][80] bf16
  float* lgw = (float*)(smem[w] + 2560);   // [32] logits
  int* cw = (int*)(smem[w] + 2816);        // [32] neighbor slots
  float* vA = (float*)(smem[w] + 3072);    // [64]
  float* vB = (float*)(smem[w] + 3328);    // [64]

  // build B-fragment images directly from global weights (L2-hot)
  for (int i = tid; i < 4096; i += 256) {
    int e = i & 7, g = i >> 3;
    int l = g & 63, q = g >> 6;
    int kb = q >> 2, nb = q & 3;
    int k = kb * 32 + ((l >> 4) & 3) * 8 + e;
    int col = nb * 16 + (l & 15);
    sB1[i] = bf16rne(S1w[k * 64 + col]);
    sB2[i] = bf16rne(S2w[k * 64 + col]);
  }
  __syncthreads();

  const int mode = flagp[0];
  const int l15 = lane & 15;
  const int lg4 = lane >> 4;
  const int b = blockIdx.x * 4 + w;        // grid 128*4 = 512 exactly
  const long uid = nodes[b];

  bool m = (lane < LSS) ? mread(social_mask, uid * LSS + lane, mode) : false;
  unsigned long long bal = __ballot(m);
  const int nval = (int)__popcll(bal);
  int pos = (int)__popcll(bal & ((1ull << lane) - 1ull));
  if (m) cw[pos] = lane;

  // inline uA1S = u @ S1w[64:128] + S1b
  const float uv = user_w[uid * 64 + lane];
  float uA1v = S1b[lane];
#pragma unroll 8
  for (int k = 0; k < 64; ++k)
    uA1v = fmaf(__shfl(uv, k), S1w[(64 + k) * 64 + lane], uA1v);
  const float a2bv = S2b[lane];
  const float a3v = S3w[lane];
  wave_fence();

  const long hbase = 512L + (long)b * 32;
  const int ng = (nval + 15) >> 4;
  for (int mc = 0; mc < ng; ++mc) {
    wave_fence();
    int row = mc * 16 + l15;
    if (row >= nval) row = nval - 1;
    const long hrow = hbase + cw[row];
    short8 xa[2];
#pragma unroll
    for (int kb = 0; kb < 2; ++kb) {
      const float* xp = hIbuf + hrow * 64 + kb * 32 + lg4 * 8;
      const float4 a = *(const float4*)xp;
      const float4 bb = *(const float4*)(xp + 4);
      short8 f;
      f[0] = bf16rne(a.x);  f[1] = bf16rne(a.y);
      f[2] = bf16rne(a.z);  f[3] = bf16rne(a.w);
      f[4] = bf16rne(bb.x); f[5] = bf16rne(bb.y);
      f[6] = bf16rne(bb.z); f[7] = bf16rne(bb.w);
      xa[kb] = f;
    }
#pragma unroll
    for (int nb = 0; nb < 4; ++nb) {
      const float ui = __shfl(uA1v, nb * 16 + l15);
      f32x4 acc = {ui, ui, ui, ui};
      acc = __builtin_amdgcn_mfma_f32_16x16x32_bf16(
          xa[0], *(const short8*)(sB1 + ((0 * 4 + nb) * 64 + lane) * 8), acc, 0, 0, 0);
      acc = __builtin_amdgcn_mfma_f32_16x16x32_bf16(
          xa[1], *(const short8*)(sB1 + ((1 * 4 + nb) * 64 + lane) * 8), acc, 0, 0, 0);
#pragma unroll
      for (int r = 0; r < 4; ++r)
        h1w[(lg4 * 4 + r) * 80 + nb * 16 + l15] = bf16rne(fmaxf(acc[r], 0.0f));
    }
    wave_fence();
    short8 ha[2];
    ha[0] = *(const short8*)(h1w + l15 * 80 + lg4 * 8);
    ha[1] = *(const short8*)(h1w + l15 * 80 + 32 + lg4 * 8);
    float t0 = 0.0f, t1 = 0.0f, t2 = 0.0f, t3 = 0.0f;
#pragma unroll
    for (int nb = 0; nb < 4; ++nb) {
      const float b2 = __shfl(a2bv, nb * 16 + l15);
      f32x4 acc = {b2, b2, b2, b2};
      acc = __builtin_amdgcn_mfma_f32_16x16x32_bf16(
          ha[0], *(const short8*)(sB2 + ((0 * 4 + nb) * 64 + lane) * 8), acc, 0, 0, 0);
      acc = __builtin_amdgcn_mfma_f32_16x16x32_bf16(
          ha[1], *(const short8*)(sB2 + ((1 * 4 + nb) * 64 + lane) * 8), acc, 0, 0, 0);
      const float a3c = __shfl(a3v, nb * 16 + l15);
      t0 = fmaf(fmaxf(acc[0], 0.0f), a3c, t0);
      t1 = fmaf(fmaxf(acc[1], 0.0f), a3c, t1);
      t2 = fmaf(fmaxf(acc[2], 0.0f), a3c, t2);
      t3 = fmaf(fmaxf(acc[3], 0.0f), a3c, t3);
    }
    t0 = rsum16(t0); t1 = rsum16(t1); t2 = rsum16(t2); t3 = rsum16(t3);
    if (l15 == 0) {
      const int jb = mc * 16 + lg4 * 4;
      lgw[jb + 0] = t0;
      lgw[jb + 1] = t1;
      lgw[jb + 2] = t2;
      lgw[jb + 3] = t3;
    }
  }
  wave_fence();

  const bool valid = (lane < nval);
  float lv = valid ? lgw[lane] : -1e30f;
  float mx = wmax(lv);
  float e = valid ? __expf(lv - mx) : 0.0f;
  float s = wsum(e);
  const float beta = e / s;

  float hs = 0.0f;
  for (int j = 0; j < nval; ++j) {
    const float bj = __shfl(beta, j);
    hs = fmaf(bj, hIbuf[(hbase + cw[j]) * 64 + lane], hs);
  }

  // ---- tail matvecs ----
  vA[lane] = hs;
  wave_fence();
  float acc = L1b[lane];
#pragma unroll 8
  for (int k = 0; k < 64; ++k) acc = fmaf(vA[k], L1w[k * 64 + lane], acc);
  const float vecB = fmaxf(acc, 0.0f);
  const float selfv = hIbuf[(long)b * 64 + lane];
  wave_fence();
  vA[lane] = selfv;
  vB[lane] = vecB;
  wave_fence();
  acc = L2b[lane];
#pragma unroll 8
  for (int k = 0; k < 64; ++k) acc = fmaf(vA[k], L2w[k * 64 + lane], acc);
#pragma unroll 8
  for (int k = 0; k < 64; ++k) acc = fmaf(vB[k], L2w[(64 + k) * 64 + lane], acc);
  const float fv = fmaxf(acc, 0.0f);
  wave_fence();
  vA[lane] = fv;
  wave_fence();
  acc = L3b[lane];
#pragma unroll 8
  for (int k = 0; k < 64; ++k) acc = fmaf(vA[k], L3w[k * 64 + lane], acc);
  out[(long)b * 64 + lane] = fmaxf(acc, 0.0f);
}

// ---------------------------------------------------------------------------
extern "C" void kernel_launch(void* const* d_in, const int* in_sizes, int n_in,
                              void* d_out, int out_size, void* d_ws, size_t ws_size,
                              hipStream_t stream) {
  const float* user_w   = (const float*)d_in[0];
  const float* item_w   = (const float*)d_in[1];
  const float* rating_w = (const float*)d_in[2];
  const float* i_ln1_w  = (const float*)d_in[3];
  const float* i_ln1_b  = (const float*)d_in[4];
  const float* i_ln2_w  = (const float*)d_in[5];
  const float* i_ln2_b  = (const float*)d_in[6];
  const float* i_ln3_w  = (const float*)d_in[7];
  const float* i_ln3_b  = (const float*)d_in[8];
  const float* i_att1_w = (const float*)d_in[9];
  const float* i_att1_b = (const float*)d_in[10];
  const float* i_att2_w = (const float*)d_in[11];
  const float* i_att2_b = (const float*)d_in[12];
  const float* i_att3_w = (const float*)d_in[13];
  const float* i_att3_b = (const float*)d_in[14];
  const float* s_ln1_w  = (const float*)d_in[15];
  const float* s_ln1_b  = (const float*)d_in[16];
  const float* s_ln2_w  = (const float*)d_in[17];
  const float* s_ln2_b  = (const float*)d_in[18];
  const float* s_ln3_w  = (const float*)d_in[19];
  const float* s_ln3_b  = (const float*)d_in[20];
  const float* s_att1_w = (const float*)d_in[21];
  const float* s_att1_b = (const float*)d_in[22];
  const float* s_att2_w = (const float*)d_in[23];
  const float* s_att2_b = (const float*)d_in[24];
  const float* s_att3_w = (const float*)d_in[25];
  const float* s_att3_b = (const float*)d_in[26];
  const int*  nodes       = (const int*)d_in[27];
  const int*  social_hist = (const int*)d_in[28];
  const void* social_mask = d_in[29];
  const int*  item_hist   = (const int*)d_in[30];
  const int*  rating_hist = (const int*)d_in[31];
  const void* item_mask   = d_in[32];

  // workspace layout (bytes) — total 21,604,096 (proven cap; do not exceed).
  // hIbuf now occupies the uA1buf region (uA1 fully consumed by the core
  // before hI2final writes) — removes the old hvecbuf alias race.
  char* ws = (char*)d_ws;
  int*   flag    = (int*)(ws + 0);          // 256
  int*   counter = (int*)(ws + 256);        // 256
  int*   list    = (int*)(ws + 512);        // NT*4 = 67584
  int*   aUid    = (int*)(ws + 68096);      // 67584
  float* uA1buf  = (float*)(ws + 135680);   // NT*64*4 = 4325376
  float* hIbuf   = uA1buf;                  // alias: uA1 dead before hI2final
  float* hvecbuf = (float*)(ws + 4461056);  // 4325376
  short* W1hi    = (short*)(ws + 4461056);  // 8192  (alias hvecbuf[0:2048])
  short* W1lo    = (short*)(ws + 4469248);  // 8192  (alias hvecbuf[2048:4096])
  float* xbase   = (float*)(ws + 8786432);  // 50000*64*4 = 12800000
  float* RW1g    = (float*)(ws + 21586432); // 1280
  short* Bimg1   = (short*)(ws + 21587712); // 8192
  short* Bimg2   = (short*)(ws + 21595904); // 8192

  hipMemsetAsync(counter, 0, 4, stream);
  setup_kernel<<<3 + NT / 256, 256, 0, stream>>>(
      (const unsigned int*)social_mask, flag,
      rating_w, i_ln1_w, i_ln1_b, RW1g,
      i_att1_w, i_att2_w, Bimg1, Bimg2, W1hi, W1lo,
      nodes, social_hist, counter, list, aUid);
  pre_xbase_mfma_kernel<<<512, 256, 0, stream>>>(item_w, W1hi, W1lo, xbase);
  uA1_kernel<<<NT / 64, 256, 0, stream>>>(user_w, i_att1_w, i_att1_b,
                                          aUid, counter, uA1buf);
  core_mfma_kernel<<<NT / 8, 512, 0, stream>>>(
      xbase, RW1g, uA1buf, Bimg1, Bimg2, i_att2_b, i_att3_w,
      item_hist, rating_hist, item_mask, flag, aUid, counter, hvecbuf);
  hI2final_kernel<<<NT / 32, 256, 0, stream>>>(
      hvecbuf, user_w, i_ln2_w, i_ln2_b, i_ln3_w, i_ln3_b,
      list, aUid, counter, hIbuf);
  social_fused_kernel<<<BB / 4, 256, 0, stream>>>(
      hIbuf, user_w, s_att1_w, s_att1_b, s_att2_w, s_att2_b, s_att3_w,
      s_ln1_w, s_ln1_b, s_ln2_w, s_ln2_b, s_ln3_w, s_ln3_b,
      nodes, social_mask, flag, (float*)d_out);
}

// Round 13
// 105.897 us; speedup vs baseline: 1.3361x; 1.0866x over previous
//
#include <hip/hip_runtime.h>
#include <math.h>

// ---------------------------------------------------------------------------
// Aggre_social on MI355X — round 13: bf16 xbase (halves the core's gather
// bytes — the measured bottleneck), pre_xbase+uA1 merged into one dispatch.
// Core schedule/structure = round 12 (proven). 6 dispatches.
// ws layout cap unchanged (21,604,096 B).
// Sizes: NU=NI=50000, NR=5, D=64, B=512, LS=32, LI=64.
// ---------------------------------------------------------------------------

#define NII 50000
#define BB 512
#define LSS 32
#define NT 16896   // 512 self + 16384 neighbor instances

typedef short short8 __attribute__((ext_vector_type(8)));
typedef float f32x4 __attribute__((ext_vector_type(4)));

static __device__ __forceinline__ bool mread(const void* p, long i, int mode) {
  if (mode == 0) return ((const int*)p)[i] != 0;       // int32 storage
  if (mode == 2) return ((const float*)p)[i] != 0.0f;  // f32 storage
  return ((const unsigned char*)p)[i] != 0;            // byte storage
}

static __device__ __forceinline__ float wsum(float v) {
#pragma unroll
  for (int s = 1; s < 64; s <<= 1) v += __shfl_xor(v, s);
  return v;
}
static __device__ __forceinline__ float wmax(float v) {
#pragma unroll
  for (int s = 1; s < 64; s <<= 1) v = fmaxf(v, __shfl_xor(v, s));
  return v;
}
static __device__ __forceinline__ float rsum16(float v) {
#pragma unroll
  for (int s = 1; s < 16; s <<= 1) v += __shfl_xor(v, s);
  return v;
}

// f32 -> bf16 (round-to-nearest-even), as raw short.
static __device__ __forceinline__ short bf16rne(float f) {
  unsigned u = __float_as_uint(f);
  u = (u + 0x7FFFu + ((u >> 16) & 1u)) >> 16;
  return (short)u;
}
static __device__ __forceinline__ float bf16tof(short h) {
  return __uint_as_float(((unsigned)(unsigned short)h) << 16);
}

// Intra-wave LDS write->read fence.
static __device__ __forceinline__ void wave_fence() {
  asm volatile("s_waitcnt lgkmcnt(0)" ::: "memory");
  __builtin_amdgcn_sched_barrier(0);
}

// ---------------------------------------------------------------------------
// K0: fused setup. block 0: mask-format detect; block 1: RW1g matvec;
// block 2: prepack item-att B-images + W1 hi/lo split; blocks 3..68: build
// active instance list (local mask-format detect per block).   <<<69,256>>>
// ---------------------------------------------------------------------------
__global__ void setup_kernel(const unsigned int* __restrict__ sm,
                             int* __restrict__ flag,
                             const float* __restrict__ rating_w,
                             const float* __restrict__ w1,
                             const float* __restrict__ b1,
                             float* __restrict__ RW1g,
                             const float* __restrict__ A1w,
                             const float* __restrict__ A2w,
                             short* __restrict__ B1,
                             short* __restrict__ B2,
                             short* __restrict__ W1hi,
                             short* __restrict__ W1lo,
                             const int* __restrict__ nodes,
                             const int* __restrict__ social_hist,
                             int* __restrict__ counter,
                             int* __restrict__ list,
                             int* __restrict__ aUid) {
  const int tid = threadIdx.x;
  if (blockIdx.x == 0) {
    __shared__ int notInt, notFloat;
    if (tid == 0) { notInt = 0; notFloat = 0; }
    __syncthreads();
    int ni = 0, nf = 0;
    for (int i = tid; i < 4096; i += 256) {
      unsigned int x = sm[i];
      if (x > 1u) ni = 1;
      if (x != 0u && x != 0x3F800000u) nf = 1;
    }
    if (ni) atomicOr(&notInt, 1);
    if (nf) atomicOr(&notFloat, 1);
    __syncthreads();
    if (tid == 0) flag[0] = notInt ? (notFloat ? 1 : 2) : 0;
  } else if (blockIdx.x == 1) {
    for (int t = tid; t < 320; t += 256) {
      const int r = t >> 6, c = t & 63;
      float acc = b1[c];
      for (int k = 0; k < 64; ++k)
        acc = fmaf(rating_w[r * 64 + k], w1[(64 + k) * 64 + c], acc);
      RW1g[r * 64 + c] = acc;
    }
  } else if (blockIdx.x == 2) {
    for (int idx = tid; idx < 4096; idx += 256) {
      int e = idx & 7, g = idx >> 3;
      int l = g & 63, q = g >> 6;        // q = kb*4+nb
      int kb = q >> 2, nb = q & 3;
      int k = kb * 32 + ((l >> 4) & 3) * 8 + e;
      int col = nb * 16 + (l & 15);
      B1[idx] = bf16rne(A1w[k * 64 + col]);
      B2[idx] = bf16rne(A2w[k * 64 + col]);
      float a = w1[k * 64 + col];
      short h = bf16rne(a);
      W1hi[idx] = h;
      W1lo[idx] = bf16rne(a - bf16tof(h));
    }
  } else {
    // build active list; per-block local mask-format detect.
    __shared__ int nI, nF;
    if (tid == 0) { nI = 0; nF = 0; }
    __syncthreads();
    int ni = 0, nf = 0;
    for (int i = tid; i < 4096; i += 256) {
      unsigned int x = sm[i];
      if (x > 1u) ni = 1;
      if (x != 0u && x != 0x3F800000u) nf = 1;
    }
    if (ni) atomicOr(&nI, 1);
    if (nf) atomicOr(&nF, 1);
    __syncthreads();
    const int mode = nI ? (nF ? 1 : 2) : 0;
    const int t = (blockIdx.x - 3) * 256 + tid;
    if (t < NT) {
      int uid;
      bool active;
      if (t < BB) {
        active = true;
        uid = nodes[t];
      } else {
        int nb = t - BB;
        int b = nb >> 5, l = nb & 31;
        long mi = (long)nodes[b] * LSS + l;
        active = mread((const void*)sm, mi, mode);
        uid = active ? social_hist[mi] : 0;
      }
      if (active) {
        int pos = atomicAdd(counter, 1);
        list[pos] = t;
        aUid[pos] = uid;
      }
    }
  }
}

// ---------------------------------------------------------------------------
// K1: merged mid-stage. blocks 0..511: xbase16[50000][64] (bf16) =
// bf16(item_w @ W1[0:64]) via split-bf16 MFMA. blocks 512..775: uA1 GEMM.
// Both only depend on setup outputs; they overlap in one dispatch.
// ---------------------------------------------------------------------------
__global__ __launch_bounds__(256, 2)
void mid_kernel(const float* __restrict__ item_w,
                const short* __restrict__ W1hi,
                const short* __restrict__ W1lo,
                short* __restrict__ xbase16,
                const float* __restrict__ user_w,
                const float* __restrict__ A1w, const float* __restrict__ A1b,
                const int* __restrict__ aUid, const int* __restrict__ nActp,
                float* __restrict__ uA1buf) {
  const int tid = threadIdx.x, lane = tid & 63, w = tid >> 6;
  if (blockIdx.x < 512) {
    // ---- pre_xbase (bf16 output) ----
    const int l15 = lane & 15, lg4 = lane >> 4;
    short8 bh[8], bl[8];                   // [kb*4+nb]
#pragma unroll
    for (int q = 0; q < 8; ++q) {
      bh[q] = *(const short8*)(W1hi + (q * 64 + lane) * 8);
      bl[q] = *(const short8*)(W1lo + (q * 64 + lane) * 8);
    }
    const int wid = blockIdx.x * 4 + w;
    for (int tile = wid; tile < 3125; tile += 2048) {
      const long r0 = (long)tile * 16;
      const float* ap = item_w + (r0 + l15) * 64 + lg4 * 8;
      short8 ah[2], al[2];
#pragma unroll
      for (int kb = 0; kb < 2; ++kb) {
        const float4 a = *(const float4*)(ap + kb * 32);
        const float4 b = *(const float4*)(ap + kb * 32 + 4);
        float v[8] = {a.x, a.y, a.z, a.w, b.x, b.y, b.z, b.w};
        short8 hi, lo;
#pragma unroll
        for (int e = 0; e < 8; ++e) {
          short h = bf16rne(v[e]);
          hi[e] = h;
          lo[e] = bf16rne(v[e] - bf16tof(h));
        }
        ah[kb] = hi;
        al[kb] = lo;
      }
#pragma unroll
      for (int nb = 0; nb < 4; ++nb) {
        f32x4 acc = {0.0f, 0.0f, 0.0f, 0.0f};
        acc = __builtin_amdgcn_mfma_f32_16x16x32_bf16(ah[0], bh[0 * 4 + nb], acc, 0, 0, 0);
        acc = __builtin_amdgcn_mfma_f32_16x16x32_bf16(ah[1], bh[1 * 4 + nb], acc, 0, 0, 0);
        acc = __builtin_amdgcn_mfma_f32_16x16x32_bf16(ah[0], bl[0 * 4 + nb], acc, 0, 0, 0);
        acc = __builtin_amdgcn_mfma_f32_16x16x32_bf16(ah[1], bl[1 * 4 + nb], acc, 0, 0, 0);
        acc = __builtin_amdgcn_mfma_f32_16x16x32_bf16(al[0], bh[0 * 4 + nb], acc, 0, 0, 0);
        acc = __builtin_amdgcn_mfma_f32_16x16x32_bf16(al[1], bh[1 * 4 + nb], acc, 0, 0, 0);
#pragma unroll
        for (int r = 0; r < 4; ++r)
          xbase16[(r0 + lg4 * 4 + r) * 64 + nb * 16 + l15] = bf16rne(acc[r]);
      }
    }
  } else {
    // ---- uA1: uA1buf[idx] = user_w[aUid[idx]] @ A1w[64:128] + A1b ----
    const int i0 = (blockIdx.x - 512) * 64;
    const int nA = nActp[0];
    if (i0 >= nA) return;
    __shared__ float sW[64][64], sU[64][64];
    __shared__ float sb[64];
    __shared__ int sUid[64];
    for (int i = tid; i < 4096; i += 256) sW[i >> 6][i & 63] = A1w[4096 + i];
    if (tid < 64) {
      sb[tid] = A1b[tid];
      sUid[tid] = (i0 + tid < nA) ? aUid[i0 + tid] : 0;
    }
    __syncthreads();
    for (int i = tid; i < 4096; i += 256) {
      int r = i >> 6, c = i & 63;
      sU[r][c] = user_w[(long)sUid[r] * 64 + c];
    }
    __syncthreads();
    float acc[16];
#pragma unroll
    for (int r = 0; r < 16; ++r) acc[r] = sb[lane];
    for (int k = 0; k < 64; k += 4) {
      float wv0 = sW[k][lane], wv1 = sW[k + 1][lane];
      float wv2 = sW[k + 2][lane], wv3 = sW[k + 3][lane];
#pragma unroll
      for (int r = 0; r < 16; ++r) {
        const float4 xv = *(const float4*)(&sU[w * 16 + r][k]);
        acc[r] = fmaf(xv.x, wv0, acc[r]);
        acc[r] = fmaf(xv.y, wv1, acc[r]);
        acc[r] = fmaf(xv.z, wv2, acc[r]);
        acc[r] = fmaf(xv.w, wv3, acc[r]);
      }
    }
#pragma unroll
    for (int r = 0; r < 16; ++r) {
      int row = i0 + w * 16 + r;
      if (row < nA) uA1buf[(long)row * 64 + lane] = acc[r];
    }
  }
}

// ---------------------------------------------------------------------------
// K5: CORE — wave-per-instance attention, MFMA bf16 logits (round-12
// schedule), xbase in bf16 (half the gather bytes). <=1 instance per wave.
// ---------------------------------------------------------------------------
__global__ __launch_bounds__(512, 8)
void core_mfma_kernel(const short* __restrict__ xb16,
                      const float* __restrict__ RW1g,
                      const float* __restrict__ uA1buf,
                      const short* __restrict__ Bimg1,
                      const short* __restrict__ Bimg2,
                      const float* __restrict__ A2b,
                      const float* __restrict__ A3w,
                      const int* __restrict__ item_hist,
                      const int* __restrict__ rating_hist,
                      const void* __restrict__ item_mask,
                      const int* __restrict__ flagp,
                      const int* __restrict__ aUid,
                      const int* __restrict__ nActp,
                      float* __restrict__ hvecbuf) {
  __shared__ __align__(16) short sB1[4096], sB2[4096];   // 16KB images
  __shared__ __align__(16) char smem[8][3072];           // 24KB wave scratch
  const int tid = threadIdx.x, lane = tid & 63, w = tid >> 6;
  const int nA = nActp[0];
  if (blockIdx.x * 8 >= nA) return;        // uniform: whole block exits

  short* h1w = (short*)(smem[w]);          // [16][80] bf16
  float* lgw = (float*)(smem[w] + 2560);   // [64] logits
  int* cw = (int*)(smem[w] + 2816);        // [64] packed (item<<3)|rating

  ((int4*)sB1)[tid] = ((const int4*)Bimg1)[tid];   // 512 * 16B = 8KB each
  ((int4*)sB2)[tid] = ((const int4*)Bimg2)[tid];
  __syncthreads();   // the only block-wide barrier

  const int idx = blockIdx.x * 8 + w;
  if (idx >= nA) return;                   // wave-level; no barriers follow

  const int mode = flagp[0];
  const float a2bv = A2b[lane];
  const float a3v = A3w[lane];
  const int l15 = lane & 15;
  const int lg4 = lane >> 4;

#define B1F(q) (*(const short8*)(sB1 + ((q) * 64 + lane) * 8))
#define B2F(q) (*(const short8*)(sB2 + ((q) * 64 + lane) * 8))

  const long uid = aUid[idx];

  // ---- compact item history (lane covers LI=64) ----
  const long mbase = uid * 64;
  bool mk = mread(item_mask, mbase + lane, mode);
  unsigned long long bal = __ballot(mk);
  const int nact = (int)__popcll(bal);
  int pos = (int)__popcll(bal & ((1ull << lane) - 1ull));
  if (mk) cw[pos] = (item_hist[mbase + lane] << 3) | rating_hist[mbase + lane];
  const float uA1v = uA1buf[(long)idx * 64 + lane];
  wave_fence();

  // ---- logits via MFMA, 16-row chunks ----
  const int ng = (nact + 15) >> 4;
  for (int mc = 0; mc < ng; ++mc) {
    wave_fence();  // prior chunk's H1 reads done before overwrite
    int row = mc * 16 + l15;
    if (row >= nact) row = nact - 1;
    const int p = cw[row];
    const long it = p >> 3;
    const int rt = p & 7;
    short8 xa[2];
#pragma unroll
    for (int kb = 0; kb < 2; ++kb) {
      const int koff = kb * 32 + lg4 * 8;
      const short8 xb = *(const short8*)(xb16 + it * 64 + koff);  // 16B
      const float* rp = RW1g + rt * 64 + koff;
      const float4 c = *(const float4*)rp;
      const float4 d = *(const float4*)(rp + 4);
      short8 f;
      f[0] = bf16rne(fmaxf(bf16tof(xb[0]) + c.x, 0.0f));
      f[1] = bf16rne(fmaxf(bf16tof(xb[1]) + c.y, 0.0f));
      f[2] = bf16rne(fmaxf(bf16tof(xb[2]) + c.z, 0.0f));
      f[3] = bf16rne(fmaxf(bf16tof(xb[3]) + c.w, 0.0f));
      f[4] = bf16rne(fmaxf(bf16tof(xb[4]) + d.x, 0.0f));
      f[5] = bf16rne(fmaxf(bf16tof(xb[5]) + d.y, 0.0f));
      f[6] = bf16rne(fmaxf(bf16tof(xb[6]) + d.z, 0.0f));
      f[7] = bf16rne(fmaxf(bf16tof(xb[7]) + d.w, 0.0f));
      xa[kb] = f;
    }
    // att1: H1 = relu(X @ A1a + uA1)
#pragma unroll
    for (int nb = 0; nb < 4; ++nb) {
      const float ui = __shfl(uA1v, nb * 16 + l15);
      f32x4 acc = {ui, ui, ui, ui};
      acc = __builtin_amdgcn_mfma_f32_16x16x32_bf16(xa[0], B1F(0 * 4 + nb), acc, 0, 0, 0);
      acc = __builtin_amdgcn_mfma_f32_16x16x32_bf16(xa[1], B1F(1 * 4 + nb), acc, 0, 0, 0);
#pragma unroll
      for (int r = 0; r < 4; ++r)
        h1w[(lg4 * 4 + r) * 80 + nb * 16 + l15] = bf16rne(fmaxf(acc[r], 0.0f));
    }
    wave_fence();
    // att2 + logit
    short8 ha[2];
    ha[0] = *(const short8*)(h1w + l15 * 80 + lg4 * 8);
    ha[1] = *(const short8*)(h1w + l15 * 80 + 32 + lg4 * 8);
    float t0 = 0.0f, t1 = 0.0f, t2 = 0.0f, t3 = 0.0f;
#pragma unroll
    for (int nb = 0; nb < 4; ++nb) {
      const float b2 = __shfl(a2bv, nb * 16 + l15);
      f32x4 acc = {b2, b2, b2, b2};
      acc = __builtin_amdgcn_mfma_f32_16x16x32_bf16(ha[0], B2F(0 * 4 + nb), acc, 0, 0, 0);
      acc = __builtin_amdgcn_mfma_f32_16x16x32_bf16(ha[1], B2F(1 * 4 + nb), acc, 0, 0, 0);
      const float a3c = __shfl(a3v, nb * 16 + l15);
      t0 = fmaf(fmaxf(acc[0], 0.0f), a3c, t0);
      t1 = fmaf(fmaxf(acc[1], 0.0f), a3c, t1);
      t2 = fmaf(fmaxf(acc[2], 0.0f), a3c, t2);
      t3 = fmaf(fmaxf(acc[3], 0.0f), a3c, t3);
    }
    t0 = rsum16(t0); t1 = rsum16(t1); t2 = rsum16(t2); t3 = rsum16(t3);
    if (l15 == 0) {
      const int jb = mc * 16 + lg4 * 4;
      lgw[jb + 0] = t0;
      lgw[jb + 1] = t1;
      lgw[jb + 2] = t2;
      lgw[jb + 3] = t3;
    }
  }
  wave_fence();

  // ---- softmax over lanes ----
  const bool valid = (lane < nact);
  float lv = valid ? lgw[lane] : -1e30f;
  float mx = wmax(lv);
  float e = valid ? __expf(lv - mx) : 0.0f;
  float s = wsum(e);
  const float alpha = e / s;

  // ---- hI = sum_j alpha_j * x_j (bf16 x re-gather, unrolled x4) ----
  float h0 = 0.0f, hA = 0.0f, hB = 0.0f, hC = 0.0f;
  int j = 0;
  for (; j + 3 < nact; j += 4) {
    const int p0 = cw[j], p1 = cw[j + 1], p2 = cw[j + 2], p3 = cw[j + 3];
    const float a0 = __shfl(alpha, j), a1 = __shfl(alpha, j + 1);
    const float a2 = __shfl(alpha, j + 2), a3 = __shfl(alpha, j + 3);
    const float x0 = bf16tof(xb16[(long)(p0 >> 3) * 64 + lane]) + RW1g[(p0 & 7) * 64 + lane];
    const float x1 = bf16tof(xb16[(long)(p1 >> 3) * 64 + lane]) + RW1g[(p1 & 7) * 64 + lane];
    const float x2 = bf16tof(xb16[(long)(p2 >> 3) * 64 + lane]) + RW1g[(p2 & 7) * 64 + lane];
    const float x3 = bf16tof(xb16[(long)(p3 >> 3) * 64 + lane]) + RW1g[(p3 & 7) * 64 + lane];
    h0 = fmaf(a0, fmaxf(x0, 0.0f), h0);
    hA = fmaf(a1, fmaxf(x1, 0.0f), hA);
    hB = fmaf(a2, fmaxf(x2, 0.0f), hB);
    hC = fmaf(a3, fmaxf(x3, 0.0f), hC);
  }
  for (; j < nact; ++j) {
    const int p = cw[j];
    const float aj = __shfl(alpha, j);
    const float xv = bf16tof(xb16[(long)(p >> 3) * 64 + lane]) + RW1g[(p & 7) * 64 + lane];
    h0 = fmaf(aj, fmaxf(xv, 0.0f), h0);
  }
  hvecbuf[(long)idx * 64 + lane] = (h0 + hA) + (hB + hC);
#undef B1F
#undef B2F
}

// ---------------------------------------------------------------------------
// K6: fused hI2 + final (round-8 high-parallelism form): 32 rows / block,
// NT/32 = 528 blocks; W buffer reloaded between the two stages.
// ---------------------------------------------------------------------------
__global__ __launch_bounds__(256, 2)
void hI2final_kernel(const float* __restrict__ hvecbuf,
                     const float* __restrict__ user_w,
                     const float* __restrict__ W2w, const float* __restrict__ W2b,
                     const float* __restrict__ W3w, const float* __restrict__ W3b,
                     const int* __restrict__ list, const int* __restrict__ aUid,
                     const int* __restrict__ nActp, float* __restrict__ hIbuf) {
  const int tid = threadIdx.x, lane = tid & 63, w = tid >> 6;
  const int i0 = blockIdx.x * 32;
  const int nA = nActp[0];
  if (i0 >= nA) return;
  __shared__ float sW[128][64];   // 32KB: W2 (rows 0..63) then W3 (0..127)
  __shared__ float sX[32][128];   // cols 0:64 = u, 64:128 = hvec then hI2
  __shared__ float sb[64];
  __shared__ int sUid[32], sInst[32];
  for (int i = tid; i < 4096; i += 256) sW[i >> 6][i & 63] = W2w[i];
  if (tid < 64) sb[tid] = W2b[tid];
  if (tid < 32) {
    bool ok = (i0 + tid) < nA;
    sUid[tid] = ok ? aUid[i0 + tid] : 0;
    sInst[tid] = ok ? list[i0 + tid] : 0;
  }
  __syncthreads();
  for (int i = tid; i < 2048; i += 256) {
    int r = i >> 6, c = i & 63;
    sX[r][64 + c] = (i0 + r < nA) ? hvecbuf[(long)(i0 + r) * 64 + c] : 0.0f;
    sX[r][c] = user_w[(long)sUid[r] * 64 + c];
  }
  __syncthreads();

  float acc[8];
  // stage A: hI2 = relu(hvec @ W2 + b2) -> sX[r][64:]
  {
    const float bv = sb[lane];
#pragma unroll
    for (int r = 0; r < 8; ++r) acc[r] = bv;
    for (int k = 0; k < 64; k += 4) {
      float wv0 = sW[k][lane], wv1 = sW[k + 1][lane];
      float wv2 = sW[k + 2][lane], wv3 = sW[k + 3][lane];
#pragma unroll
      for (int r = 0; r < 8; ++r) {
        const float4 xv = *(const float4*)(&sX[w * 8 + r][64 + k]);
        acc[r] = fmaf(xv.x, wv0, acc[r]);
        acc[r] = fmaf(xv.y, wv1, acc[r]);
        acc[r] = fmaf(xv.z, wv2, acc[r]);
        acc[r] = fmaf(xv.w, wv3, acc[r]);
      }
    }
#pragma unroll
    for (int r = 0; r < 8; ++r) sX[w * 8 + r][64 + lane] = fmaxf(acc[r], 0.0f);
  }
  __syncthreads();
  for (int i = tid; i < 8192; i += 256) sW[i >> 6][i & 63] = W3w[i];
  if (tid < 64) sb[tid] = W3b[tid];
  __syncthreads();

  // stage B: out = relu([u ; hI2] @ W3 + b3)
  {
    const float bv = sb[lane];
#pragma unroll
    for (int r = 0; r < 8; ++r) acc[r] = bv;
    for (int k = 0; k < 128; k += 4) {
      float wv0 = sW[k][lane], wv1 = sW[k + 1][lane];
      float wv2 = sW[k + 2][lane], wv3 = sW[k + 3][lane];
#pragma unroll
      for (int r = 0; r < 8; ++r) {
        const float4 xv = *(const float4*)(&sX[w * 8 + r][k]);
        acc[r] = fmaf(xv.x, wv0, acc[r]);
        acc[r] = fmaf(xv.y, wv1, acc[r]);
        acc[r] = fmaf(xv.z, wv2, acc[r]);
        acc[r] = fmaf(xv.w, wv3, acc[r]);
      }
    }
#pragma unroll
    for (int r = 0; r < 8; ++r) {
      int row = i0 + w * 8 + r;
      if (row < nA)
        hIbuf[(long)sInst[w * 8 + r] * 64 + lane] = fmaxf(acc[r], 0.0f);
    }
  }
}

// ---------------------------------------------------------------------------
// K7: fully fused social phase — one wave per batch element b. B-images
// built in-kernel from s_att1/s_att2.
// ---------------------------------------------------------------------------
__global__ __launch_bounds__(256, 8)
void social_fused_kernel(const float* __restrict__ hIbuf,
                         const float* __restrict__ user_w,
                         const float* __restrict__ S1w,   // s_att1_w [128][64]
                         const float* __restrict__ S1b,
                         const float* __restrict__ S2w,   // s_att2_w [64][64]
                         const float* __restrict__ S2b,
                         const float* __restrict__ S3w,
                         const float* __restrict__ L1w, const float* __restrict__ L1b,
                         const float* __restrict__ L2w, const float* __restrict__ L2b,
                         const float* __restrict__ L3w, const float* __restrict__ L3b,
                         const int* __restrict__ nodes,
                         const void* __restrict__ social_mask,
                         const int* __restrict__ flagp,
                         float* __restrict__ out) {
  __shared__ __align__(16) short sB1[4096], sB2[4096];   // 16KB images
  __shared__ __align__(16) char smem[4][3584];           // 14KB wave scratch
  const int tid = threadIdx.x, lane = tid & 63, w = tid >> 6;
  short* h1w = (short*)(smem[w]);          // [16][80] bf16
  float* lgw = (float*)(smem[w] + 2560);   // [32] logits
  int* cw = (int*)(smem[w] + 2816);        // [32] neighbor slots
  float* vA = (float*)(smem[w] + 3072);    // [64]
  float* vB = (float*)(smem[w] + 3328);    // [64]

  // build B-fragment images directly from global weights (L2-hot)
  for (int i = tid; i < 4096; i += 256) {
    int e = i & 7, g = i >> 3;
    int l = g & 63, q = g >> 6;
    int kb = q >> 2, nb = q & 3;
    int k = kb * 32 + ((l >> 4) & 3) * 8 + e;
    int col = nb * 16 + (l & 15);
    sB1[i] = bf16rne(S1w[k * 64 + col]);
    sB2[i] = bf16rne(S2w[k * 64 + col]);
  }
  __syncthreads();

  const int mode = flagp[0];
  const int l15 = lane & 15;
  const int lg4 = lane >> 4;
  const int b = blockIdx.x * 4 + w;        // grid 128*4 = 512 exactly
  const long uid = nodes[b];

  bool m = (lane < LSS) ? mread(social_mask, uid * LSS + lane, mode) : false;
  unsigned long long bal = __ballot(m);
  const int nval = (int)__popcll(bal);
  int pos = (int)__popcll(bal & ((1ull << lane) - 1ull));
  if (m) cw[pos] = lane;

  // inline uA1S = u @ S1w[64:128] + S1b
  const float uv = user_w[uid * 64 + lane];
  float uA1v = S1b[lane];
#pragma unroll 8
  for (int k = 0; k < 64; ++k)
    uA1v = fmaf(__shfl(uv, k), S1w[(64 + k) * 64 + lane], uA1v);
  const float a2bv = S2b[lane];
  const float a3v = S3w[lane];
  wave_fence();

  const long hbase = 512L + (long)b * 32;
  const int ng = (nval + 15) >> 4;
  for (int mc = 0; mc < ng; ++mc) {
    wave_fence();
    int row = mc * 16 + l15;
    if (row >= nval) row = nval - 1;
    const long hrow = hbase + cw[row];
    short8 xa[2];
#pragma unroll
    for (int kb = 0; kb < 2; ++kb) {
      const float* xp = hIbuf + hrow * 64 + kb * 32 + lg4 * 8;
      const float4 a = *(const float4*)xp;
      const float4 bb = *(const float4*)(xp + 4);
      short8 f;
      f[0] = bf16rne(a.x);  f[1] = bf16rne(a.y);
      f[2] = bf16rne(a.z);  f[3] = bf16rne(a.w);
      f[4] = bf16rne(bb.x); f[5] = bf16rne(bb.y);
      f[6] = bf16rne(bb.z); f[7] = bf16rne(bb.w);
      xa[kb] = f;
    }
#pragma unroll
    for (int nb = 0; nb < 4; ++nb) {
      const float ui = __shfl(uA1v, nb * 16 + l15);
      f32x4 acc = {ui, ui, ui, ui};
      acc = __builtin_amdgcn_mfma_f32_16x16x32_bf16(
          xa[0], *(const short8*)(sB1 + ((0 * 4 + nb) * 64 + lane) * 8), acc, 0, 0, 0);
      acc = __builtin_amdgcn_mfma_f32_16x16x32_bf16(
          xa[1], *(const short8*)(sB1 + ((1 * 4 + nb) * 64 + lane) * 8), acc, 0, 0, 0);
#pragma unroll
      for (int r = 0; r < 4; ++r)
        h1w[(lg4 * 4 + r) * 80 + nb * 16 + l15] = bf16rne(fmaxf(acc[r], 0.0f));
    }
    wave_fence();
    short8 ha[2];
    ha[0] = *(const short8*)(h1w + l15 * 80 + lg4 * 8);
    ha[1] = *(const short8*)(h1w + l15 * 80 + 32 + lg4 * 8);
    float t0 = 0.0f, t1 = 0.0f, t2 = 0.0f, t3 = 0.0f;
#pragma unroll
    for (int nb = 0; nb < 4; ++nb) {
      const float b2 = __shfl(a2bv, nb * 16 + l15);
      f32x4 acc = {b2, b2, b2, b2};
      acc = __builtin_amdgcn_mfma_f32_16x16x32_bf16(
          ha[0], *(const short8*)(sB2 + ((0 * 4 + nb) * 64 + lane) * 8), acc, 0, 0, 0);
      acc = __builtin_amdgcn_mfma_f32_16x16x32_bf16(
          ha[1], *(const short8*)(sB2 + ((1 * 4 + nb) * 64 + lane) * 8), acc, 0, 0, 0);
      const float a3c = __shfl(a3v, nb * 16 + l15);
      t0 = fmaf(fmaxf(acc[0], 0.0f), a3c, t0);
      t1 = fmaf(fmaxf(acc[1], 0.0f), a3c, t1);
      t2 = fmaf(fmaxf(acc[2], 0.0f), a3c, t2);
      t3 = fmaf(fmaxf(acc[3], 0.0f), a3c, t3);
    }
    t0 = rsum16(t0); t1 = rsum16(t1); t2 = rsum16(t2); t3 = rsum16(t3);
    if (l15 == 0) {
      const int jb = mc * 16 + lg4 * 4;
      lgw[jb + 0] = t0;
      lgw[jb + 1] = t1;
      lgw[jb + 2] = t2;
      lgw[jb + 3] = t3;
    }
  }
  wave_fence();

  const bool valid = (lane < nval);
  float lv = valid ? lgw[lane] : -1e30f;
  float mx = wmax(lv);
  float e = valid ? __expf(lv - mx) : 0.0f;
  float s = wsum(e);
  const float beta = e / s;

  float hs = 0.0f;
  for (int j = 0; j < nval; ++j) {
    const float bj = __shfl(beta, j);
    hs = fmaf(bj, hIbuf[(hbase + cw[j]) * 64 + lane], hs);
  }

  // ---- tail matvecs ----
  vA[lane] = hs;
  wave_fence();
  float acc = L1b[lane];
#pragma unroll 8
  for (int k = 0; k < 64; ++k) acc = fmaf(vA[k], L1w[k * 64 + lane], acc);
  const float vecB = fmaxf(acc, 0.0f);
  const float selfv = hIbuf[(long)b * 64 + lane];
  wave_fence();
  vA[lane] = selfv;
  vB[lane] = vecB;
  wave_fence();
  acc = L2b[lane];
#pragma unroll 8
  for (int k = 0; k < 64; ++k) acc = fmaf(vA[k], L2w[k * 64 + lane], acc);
#pragma unroll 8
  for (int k = 0; k < 64; ++k) acc = fmaf(vB[k], L2w[(64 + k) * 64 + lane], acc);
  const float fv = fmaxf(acc, 0.0f);
  wave_fence();
  vA[lane] = fv;
  wave_fence();
  acc = L3b[lane];
#pragma unroll 8
  for (int k = 0; k < 64; ++k) acc = fmaf(vA[k], L3w[k * 64 + lane], acc);
  out[(long)b * 64 + lane] = fmaxf(acc, 0.0f);
}

// ---------------------------------------------------------------------------
extern "C" void kernel_launch(void* const* d_in, const int* in_sizes, int n_in,
                              void* d_out, int out_size, void* d_ws, size_t ws_size,
                              hipStream_t stream) {
  const float* user_w   = (const float*)d_in[0];
  const float* item_w   = (const float*)d_in[1];
  const float* rating_w = (const float*)d_in[2];
  const float* i_ln1_w  = (const float*)d_in[3];
  const float* i_ln1_b  = (const float*)d_in[4];
  const float* i_ln2_w  = (const float*)d_in[5];
  const float* i_ln2_b  = (const float*)d_in[6];
  const float* i_ln3_w  = (const float*)d_in[7];
  const float* i_ln3_b  = (const float*)d_in[8];
  const float* i_att1_w = (const float*)d_in[9];
  const float* i_att1_b = (const float*)d_in[10];
  const float* i_att2_w = (const float*)d_in[11];
  const float* i_att2_b = (const float*)d_in[12];
  const float* i_att3_w = (const float*)d_in[13];
  const float* i_att3_b = (const float*)d_in[14];
  const float* s_ln1_w  = (const float*)d_in[15];
  const float* s_ln1_b  = (const float*)d_in[16];
  const float* s_ln2_w  = (const float*)d_in[17];
  const float* s_ln2_b  = (const float*)d_in[18];
  const float* s_ln3_w  = (const float*)d_in[19];
  const float* s_ln3_b  = (const float*)d_in[20];
  const float* s_att1_w = (const float*)d_in[21];
  const float* s_att1_b = (const float*)d_in[22];
  const float* s_att2_w = (const float*)d_in[23];
  const float* s_att2_b = (const float*)d_in[24];
  const float* s_att3_w = (const float*)d_in[25];
  const float* s_att3_b = (const float*)d_in[26];
  const int*  nodes       = (const int*)d_in[27];
  const int*  social_hist = (const int*)d_in[28];
  const void* social_mask = d_in[29];
  const int*  item_hist   = (const int*)d_in[30];
  const int*  rating_hist = (const int*)d_in[31];
  const void* item_mask   = d_in[32];

  // workspace layout (bytes) — total 21,604,096 (proven cap; do not exceed).
  // xbase now bf16 (6.4MB) in the old 12.8MB slot.
  char* ws = (char*)d_ws;
  int*   flag    = (int*)(ws + 0);          // 256
  int*   counter = (int*)(ws + 256);        // 256
  int*   list    = (int*)(ws + 512);        // NT*4 = 67584
  int*   aUid    = (int*)(ws + 68096);      // 67584
  float* uA1buf  = (float*)(ws + 135680);   // NT*64*4 = 4325376
  float* hIbuf   = uA1buf;                  // alias: uA1 dead before hI2final
  float* hvecbuf = (float*)(ws + 4461056);  // 4325376
  short* W1hi    = (short*)(ws + 4461056);  // 8192  (alias hvecbuf[0:2048])
  short* W1lo    = (short*)(ws + 4469248);  // 8192  (alias hvecbuf[2048:4096])
  short* xbase16 = (short*)(ws + 8786432);  // 50000*64*2 = 6400000
  float* RW1g    = (float*)(ws + 21586432); // 1280
  short* Bimg1   = (short*)(ws + 21587712); // 8192
  short* Bimg2   = (short*)(ws + 21595904); // 8192

  hipMemsetAsync(counter, 0, 4, stream);
  setup_kernel<<<3 + NT / 256, 256, 0, stream>>>(
      (const unsigned int*)social_mask, flag,
      rating_w, i_ln1_w, i_ln1_b, RW1g,
      i_att1_w, i_att2_w, Bimg1, Bimg2, W1hi, W1lo,
      nodes, social_hist, counter, list, aUid);
  mid_kernel<<<512 + NT / 64, 256, 0, stream>>>(
      item_w, W1hi, W1lo, xbase16,
      user_w, i_att1_w, i_att1_b, aUid, counter, uA1buf);
  core_mfma_kernel<<<NT / 8, 512, 0, stream>>>(
      xbase16, RW1g, uA1buf, Bimg1, Bimg2, i_att2_b, i_att3_w,
      item_hist, rating_hist, item_mask, flag, aUid, counter, hvecbuf);
  hI2final_kernel<<<NT / 32, 256, 0, stream>>>(
      hvecbuf, user_w, i_ln2_w, i_ln2_b, i_ln3_w, i_ln3_b,
      list, aUid, counter, hIbuf);
  social_fused_kernel<<<BB / 4, 256, 0, stream>>>(
      hIbuf, user_w, s_att1_w, s_att1_b, s_att2_w, s_att2_b, s_att3_w,
      s_ln1_w, s_ln1_b, s_ln2_w, s_ln2_b, s_ln3_w, s_ln3_b,
      nodes, social_mask, flag, (float*)d_out);
}